// Round 5
// baseline (724.413 us; speedup 1.0000x reference)
//
#include <hip/hip_runtime.h>
#include <hip/hip_bf16.h>

#define NODES 16384
#define FEAT 512   // H*DH
typedef __hip_bfloat16 bf16;
typedef __hip_bfloat162 bf162;

static __device__ __forceinline__ float ldf(const float* p){ return *p; }
static __device__ __forceinline__ float ldf(const bf16* p){ return __bfloat162float(*p); }
static __device__ __forceinline__ void stf(float* p, float v){ *p = v; }
static __device__ __forceinline__ void stf(bf16* p, float v){ *p = __float2bfloat16(v); }

// ---------------- diagnostic sentinel ----------------
__global__ void sentinel_kernel(float* __restrict__ out, int n, float v){
  int i = blockIdx.x*blockDim.x + threadIdx.x;
  if (i < n) out[i] = v;
}

// ---------------- CSR build ----------------
__global__ void zero_kernel(int* __restrict__ p, int n){
  int i = blockIdx.x*blockDim.x + threadIdx.x;
  if (i < n) p[i] = 0;
}

__global__ void count_kernel(const int* __restrict__ ei, int* __restrict__ counts, int E){
  int i = blockIdx.x*blockDim.x + threadIdx.x;
  if (i < 2*E){
    int dst = (i < E) ? ei[E+i] : ei[i-E];
    atomicAdd(&counts[dst], 1);
  }
}

__global__ __launch_bounds__(1024) void scan_kernel(const int* __restrict__ counts,
                                                    int* __restrict__ offs, int* __restrict__ cursor){
  __shared__ int sh[1024];
  const int t = threadIdx.x;
  int loc[16];
  int s = 0;
#pragma unroll
  for (int i=0;i<16;i++){ loc[i] = counts[t*16+i]; s += loc[i]; }
  sh[t] = s;
  __syncthreads();
  for (int d=1; d<1024; d<<=1){
    int v = (t>=d) ? sh[t-d] : 0;
    __syncthreads();
    sh[t] += v;
    __syncthreads();
  }
  int run = (t==0) ? 0 : sh[t-1];
#pragma unroll
  for (int i=0;i<16;i++){ offs[t*16+i] = run; cursor[t*16+i] = run; run += loc[i]; }
  if (t==1023) offs[NODES] = run;
}

__global__ void fill_kernel(const int* __restrict__ ei, int* __restrict__ cursor,
                            int* __restrict__ csr_src, int E){
  int i = blockIdx.x*blockDim.x + threadIdx.x;
  if (i < 2*E){
    int src = ei[i];
    int dst = (i < E) ? ei[E+i] : ei[i-E];
    int pos = atomicAdd(&cursor[dst], 1);
    csr_src[pos] = src;
  }
}

// ---------------- GEMM: C[MxN] = A[MxK] @ B[KxN] (+bias)(+relu) ----------------
template<typename AT, typename CT, int ACT>
__global__ __launch_bounds__(256) void gemm_kernel(const AT* __restrict__ A,
    const float* __restrict__ B, const float* __restrict__ bias,
    CT* __restrict__ C, int K_, int N_){
  __shared__ float As[16][66];
  __shared__ float Bs[16][66];
  const int tid = threadIdx.x;
  const int tx = tid & 15, ty = tid >> 4;
  const int row0 = blockIdx.y*64, col0 = blockIdx.x*64;
  float acc[4][4] = {};
  for (int k0 = 0; k0 < K_; k0 += 16){
#pragma unroll
    for (int i = tid; i < 1024; i += 256){
      int r = i >> 4, kk = i & 15;
      As[kk][r] = ldf(&A[(size_t)(row0+r)*K_ + k0 + kk]);
    }
#pragma unroll
    for (int i = tid; i < 1024; i += 256){
      int kk = i >> 6, c = i & 63;
      Bs[kk][c] = B[(size_t)(k0+kk)*N_ + col0 + c];
    }
    __syncthreads();
#pragma unroll
    for (int kk=0; kk<16; kk++){
      float a[4], b[4];
#pragma unroll
      for (int i=0;i<4;i++) a[i] = As[kk][ty*4+i];
#pragma unroll
      for (int j=0;j<4;j++) b[j] = Bs[kk][tx*4+j];
#pragma unroll
      for (int i=0;i<4;i++)
#pragma unroll
        for (int j=0;j<4;j++) acc[i][j] += a[i]*b[j];
    }
    __syncthreads();
  }
#pragma unroll
  for (int i=0;i<4;i++){
    int row = row0 + ty*4 + i;
#pragma unroll
    for (int j=0;j<4;j++){
      int col = col0 + tx*4 + j;
      float v = acc[i][j];
      if (bias) v += bias[col];
      if (ACT == 1) v = fmaxf(v, 0.f);
      stf(&C[(size_t)row*N_ + col], v);
    }
  }
}

// ---------------- attention coefficients: als/ald per (node, head) ----------------
__global__ __launch_bounds__(256) void alsald_kernel(const bf16* __restrict__ h,
    const float* __restrict__ a_s, const float* __restrict__ a_d,
    float* __restrict__ als, float* __restrict__ ald){
  int n = blockIdx.x;
  int w = threadIdx.x >> 6, lane = threadIdx.x & 63;
  int c = w*128 + lane*2;
  bf162 hv = *(const bf162*)&h[(size_t)n*FEAT + c];
  float hx = __bfloat162float(hv.x), hy = __bfloat162float(hv.y);
  float2 as2 = *(const float2*)&a_s[c];
  float2 ad2 = *(const float2*)&a_d[c];
  float s = hx*as2.x + hy*as2.y;
  float d = hx*ad2.x + hy*ad2.y;
#pragma unroll
  for (int o=32;o>0;o>>=1){ s += __shfl_xor(s,o); d += __shfl_xor(d,o); }
  if (lane == 0){ als[n*4+w] = s; ald[n*4+w] = d; }
}

// ---------------- GAT aggregation: one block per dst node, one wave per head ----------------
template<bool CONCAT, typename OT>
__global__ __launch_bounds__(256) void gat_agg_kernel(const bf16* __restrict__ hfeat,
    const float* __restrict__ als, const float* __restrict__ ald,
    const int* __restrict__ offs, const int* __restrict__ csr_src,
    const float* __restrict__ bias, OT* __restrict__ out){
  int n = blockIdx.x;
  int w = threadIdx.x >> 6, lane = threadIdx.x & 63;
  float aldn = ald[n*4+w];
  int beg = offs[n], end = offs[n+1];
  float m = -1e30f, den = 0.f, a0 = 0.f, a1 = 0.f;
  for (int idx = beg; idx <= end; ++idx){
    int src = (idx < end) ? csr_src[idx] : n;   // self-loop appended implicitly
    float e = als[src*4+w] + aldn;
    e = e > 0.f ? e : 0.2f*e;                    // leaky_relu 0.2
    float mn = fmaxf(m, e);
    float sc = __expf(m - mn);
    float p  = __expf(e - mn);
    bf162 hv = *(const bf162*)&hfeat[(size_t)src*FEAT + w*128 + lane*2];
    den = den*sc + p;
    a0 = a0*sc + p*__bfloat162float(hv.x);
    a1 = a1*sc + p*__bfloat162float(hv.y);
    m = mn;
  }
  float inv = 1.f/(den + 1e-16f);
  a0 *= inv; a1 *= inv;
  if (CONCAT){
    int c = w*128 + lane*2;
    float v0 = a0 + bias[c];
    float v1 = a1 + bias[c+1];
    v0 = v0 > 0.f ? v0 : expm1f(v0);             // ELU fused
    v1 = v1 > 0.f ? v1 : expm1f(v1);
    stf(&out[(size_t)n*FEAT + c],     v0);
    stf(&out[(size_t)n*FEAT + c + 1], v1);
  } else {
    __shared__ float red[4][128];
    red[w][lane*2]   = a0;
    red[w][lane*2+1] = a1;
    __syncthreads();
    if (w == 0){
#pragma unroll
      for (int j = lane; j < 128; j += 64){
        float sum = red[0][j] + red[1][j] + red[2][j] + red[3][j];
        stf(&out[(size_t)n*128 + j], 0.25f*sum + bias[j]);  // head mean + b2
      }
    }
  }
}

// ---------------- q = h2 + pe[L-1] (in place, f32) ----------------
__global__ void add_pe_kernel(float* __restrict__ h2, int total){
  int i = blockIdx.x*blockDim.x + threadIdx.x;
  if (i < total){
    int j = i & 127;
    float ex = __expf((float)(j & ~1) * (-9.210340371976184f/128.f)); // exp(2i * -ln(1e4)/D)
    float pe = (j & 1) ? cosf(4.f*ex) : sinf(4.f*ex);
    h2[i] += pe;
  }
}

// ---------------- LayerNorm(a+b) ----------------
__global__ __launch_bounds__(256) void ln_kernel(const float* __restrict__ a, const float* __restrict__ b,
    const float* __restrict__ g, const float* __restrict__ bb, float* __restrict__ out){
  int row = blockIdx.x*4 + (threadIdx.x >> 6);
  int lane = threadIdx.x & 63;
  int c = lane*2;
  float2 va = *(const float2*)&a[(size_t)row*128 + c];
  float2 vb = *(const float2*)&b[(size_t)row*128 + c];
  float x0 = va.x+vb.x, x1 = va.y+vb.y;
  float s = x0+x1, q = x0*x0 + x1*x1;
#pragma unroll
  for (int o=32;o>0;o>>=1){ s += __shfl_xor(s,o); q += __shfl_xor(q,o); }
  float mu = s*(1.f/128.f);
  float var = q*(1.f/128.f) - mu*mu;
  float r = 1.f/sqrtf(var + 1e-5f);
  out[(size_t)row*128 + c]   = (x0-mu)*r*g[c]   + bb[c];
  out[(size_t)row*128 + c+1] = (x1-mu)*r*g[c+1] + bb[c+1];
}

// ---------------- final: out = y @ wc(128x2) + bc, f32 out ----------------
__global__ __launch_bounds__(256) void final_kernel(const float* __restrict__ y,
    const float* __restrict__ wc, const float* __restrict__ bc,
    float* __restrict__ out){
  int row = blockIdx.x*4 + (threadIdx.x >> 6);
  int lane = threadIdx.x & 63;
  int k = lane*2;
  float2 v = *(const float2*)&y[(size_t)row*128 + k];
  float s0 = v.x*wc[k*2]   + v.y*wc[(k+1)*2];
  float s1 = v.x*wc[k*2+1] + v.y*wc[(k+1)*2+1];
#pragma unroll
  for (int o=32;o>0;o>>=1){ s0 += __shfl_xor(s0,o); s1 += __shfl_xor(s1,o); }
  if (lane == 0){
    out[row*2]   = s0 + bc[0];
    out[row*2+1] = s1 + bc[1];
  }
}

extern "C" void kernel_launch(void* const* d_in, const int* in_sizes, int n_in,
                              void* d_out, int out_size, void* d_ws, size_t ws_size,
                              hipStream_t stream){
  const float* x      = (const float*)d_in[0];
  const int*   ei     = (const int*)d_in[1];
  const float* W1     = (const float*)d_in[3];
  const float* a_src1 = (const float*)d_in[4];
  const float* a_dst1 = (const float*)d_in[5];
  const float* b1     = (const float*)d_in[6];
  const float* W2     = (const float*)d_in[7];
  const float* a_src2 = (const float*)d_in[8];
  const float* a_dst2 = (const float*)d_in[9];
  const float* b2     = (const float*)d_in[10];
  // d_in[11..14] = wq,bq,wk,bk : unused (temporal softmax mask is one-hot at l=L-1)
  const float* wv     = (const float*)d_in[15];
  const float* bv     = (const float*)d_in[16];
  const float* wo     = (const float*)d_in[17];
  const float* bo     = (const float*)d_in[18];
  const float* ln_g   = (const float*)d_in[19];
  const float* ln_b   = (const float*)d_in[20];
  const float* f1     = (const float*)d_in[21];
  const float* fb1    = (const float*)d_in[22];
  const float* f2     = (const float*)d_in[23];
  const float* fb2    = (const float*)d_in[24];
  const float* wc     = (const float*)d_in[25];
  const float* bc     = (const float*)d_in[26];
  float* outp = (float*)d_out;   // reference output dtype is float32

  const int E = in_sizes[1] / 2;   // 262144
  const int n = NODES;
  const int tE = 2*E;
  const size_t MB = 1024*1024;

  // ---- workspace probe: if too small, report ws_size via the absmax error ----
  const size_t NEED = 36*MB;
  if (ws_size < NEED){
    sentinel_kernel<<<(out_size+255)/256, 256, 0, stream>>>(outp, out_size,
        1000.0f + (float)(ws_size / MB));
    return;
  }

  // ---- packed arena: P=[0,16MB) Q=[16,32MB) S=[32,~35.3MB) ----
  char* base = (char*)d_ws;
  bf16*  h1     = (bf16*)(base + 0);        // P      : h1 bf16 N*512   (gemm1 -> agg1)
  bf16*  h      = (bf16*)(base + 16*MB);    // Q      : h  bf16 N*512   (agg1 -> gemm2)
  bf16*  h2f    = (bf16*)(base + 0);        // P      : h2 feats bf16   (gemm2 -> agg2; h1 dead)
  float* h2q    = (float*)(base + 16*MB);   // Q[0:8] : h2/q f32 N*128  (agg2 -> ln1; h dead)
  float* vbuf   = (float*)(base + 0);       // P[0:8] : v   (h2f dead after agg2)
  float* aobuf  = (float*)(base + 8*MB);    // P[8:16]: ao
  float* y1     = (float*)(base + 24*MB);   // Q[8:16]: ln1 out
  bf16*  hidden = (bf16*)(base + 0);        // P      : ffn hidden bf16 N*512 (vbuf/aobuf dead)
  float* ffn2   = (float*)(base + 16*MB);   // Q[0:8] : ffn out (h2q dead)
  float* y2     = (float*)(base + 0);       // P[0:8] : ln2 out (hidden dead)
  // small arrays in S:
  char* u = base + 32*MB;
  float* als1 = (float*)(u);            u += (size_t)n*4*4;
  float* ald1 = (float*)(u);            u += (size_t)n*4*4;
  float* als2 = (float*)(u);            u += (size_t)n*4*4;
  float* ald2 = (float*)(u);            u += (size_t)n*4*4;
  int* counts = (int*)(u);              u += (size_t)n*4;
  int* offs   = (int*)(u);              u += (size_t)(n+1)*4 + 252;
  int* cursor = (int*)(u);              u += (size_t)n*4;
  int* csr    = (int*)(u);              u += (size_t)tE*4;

  // ---- CSR build ----
  zero_kernel<<<(n+255)/256, 256, 0, stream>>>(counts, n);
  count_kernel<<<(tE+255)/256, 256, 0, stream>>>(ei, counts, E);
  scan_kernel<<<1, 1024, 0, stream>>>(counts, offs, cursor);
  fill_kernel<<<(tE+255)/256, 256, 0, stream>>>(ei, cursor, csr, E);

  // ---- GAT layer 1 ----
  gemm_kernel<float,bf16,0><<<dim3(8, 256), 256, 0, stream>>>(x, W1, nullptr, h1, 128, 512);
  alsald_kernel<<<n, 256, 0, stream>>>(h1, a_src1, a_dst1, als1, ald1);
  gat_agg_kernel<true,bf16><<<n, 256, 0, stream>>>(h1, als1, ald1, offs, csr, b1, h);

  // ---- GAT layer 2 ----
  gemm_kernel<bf16,bf16,0><<<dim3(8, 256), 256, 0, stream>>>(h, W2, nullptr, h2f, 512, 512);
  alsald_kernel<<<n, 256, 0, stream>>>(h2f, a_src2, a_dst2, als2, ald2);
  gat_agg_kernel<false,float><<<n, 256, 0, stream>>>(h2f, als2, ald2, offs, csr, b2, h2q);

  // ---- temporal attention (collapsed to V at l=L-1) + head ----
  add_pe_kernel<<<(n*128+255)/256, 256, 0, stream>>>(h2q, n*128);
  gemm_kernel<float,float,0><<<dim3(2, 256), 256, 0, stream>>>(h2q, wv, bv, vbuf, 128, 128);
  gemm_kernel<float,float,0><<<dim3(2, 256), 256, 0, stream>>>(vbuf, wo, bo, aobuf, 128, 128);
  ln_kernel<<<n/4, 256, 0, stream>>>(h2q, aobuf, ln_g, ln_b, y1);
  gemm_kernel<float,bf16,1><<<dim3(8, 256), 256, 0, stream>>>(y1, f1, fb1, hidden, 128, 512);
  gemm_kernel<bf16,float,0><<<dim3(2, 256), 256, 0, stream>>>(hidden, f2, fb2, ffn2, 512, 128);
  ln_kernel<<<n/4, 256, 0, stream>>>(y1, ffn2, ln_g, ln_b, y2);
  final_kernel<<<n/4, 256, 0, stream>>>(y2, wc, bc, outp);
}

// Round 8
// 486.522 us; speedup vs baseline: 1.4890x; 1.4890x over previous
//
#include <hip/hip_runtime.h>
#include <hip/hip_bf16.h>

#define NODES 16384
#define FEAT 512
typedef __hip_bfloat16 bf16;
typedef __hip_bfloat162 bf162;
typedef short short8v __attribute__((ext_vector_type(8)));
typedef float f32x4 __attribute__((ext_vector_type(4)));

static __device__ __forceinline__ float b2f(short s){
  return __uint_as_float(((unsigned)(unsigned short)s) << 16);
}
static __device__ __forceinline__ void split_store(bf16* h, bf16* l, size_t i, float v){
  bf16 hi = __float2bfloat16(v);
  h[i] = hi; l[i] = __float2bfloat16(v - __bfloat162float(hi));
}

// ---------------- diagnostic sentinel ----------------
__global__ void sentinel_kernel(float* __restrict__ out, int n, float v){
  int i = blockIdx.x*blockDim.x + threadIdx.x;
  if (i < n) out[i] = v;
}

// ---------------- CSR build ----------------
__global__ void zero_kernel(int* __restrict__ p, int n){
  int i = blockIdx.x*blockDim.x + threadIdx.x;
  if (i < n) p[i] = 0;
}
__global__ void count_kernel(const int* __restrict__ ei, int* __restrict__ counts, int E){
  int i = blockIdx.x*blockDim.x + threadIdx.x;
  if (i < 2*E){
    int dst = (i < E) ? ei[E+i] : ei[i-E];
    atomicAdd(&counts[dst], 1);
  }
}
__global__ __launch_bounds__(1024) void scan_kernel(const int* __restrict__ counts,
                                                    int* __restrict__ offs, int* __restrict__ cursor){
  __shared__ int sh[1024];
  const int t = threadIdx.x;
  int loc[16]; int s = 0;
#pragma unroll
  for (int i=0;i<16;i++){ loc[i] = counts[t*16+i]; s += loc[i]; }
  sh[t] = s; __syncthreads();
  for (int d=1; d<1024; d<<=1){
    int v = (t>=d) ? sh[t-d] : 0;
    __syncthreads(); sh[t] += v; __syncthreads();
  }
  int run = (t==0) ? 0 : sh[t-1];
#pragma unroll
  for (int i=0;i<16;i++){ offs[t*16+i] = run; cursor[t*16+i] = run; run += loc[i]; }
  if (t==1023) offs[NODES] = run;
}
__global__ void fill_kernel(const int* __restrict__ ei, int* __restrict__ cursor,
                            unsigned short* __restrict__ csr, int E){
  int i = blockIdx.x*blockDim.x + threadIdx.x;
  if (i < 2*E){
    int src = ei[i];
    int dst = (i < E) ? ei[E+i] : ei[i-E];
    int pos = atomicAdd(&cursor[dst], 1);
    csr[pos] = (unsigned short)src;
  }
}

// ---------------- prep: split x + transpose/split all weights to bf16 pairs ----------------
struct PrepArgs {
  const float *x,*W1,*W2,*wv,*wo,*f1,*f2;
  bf16 *xh,*xl,*w1h,*w1l,*w2h,*w2l,*wvh,*wvl,*woh,*wol,*f1h,*f1l,*f2h,*f2l;
};
__global__ void prep_kernel(PrepArgs P){
  int i = blockIdx.x*blockDim.x + threadIdx.x;
  if (i < 2097152){ split_store(P.xh, P.xl, i, P.x[i]); return; }
  i -= 2097152;
  if (i < 65536){ split_store(P.w1h, P.w1l, i, P.W1[(i&127)*512 + (i>>7)]); return; }   // K=128,N=512
  i -= 65536;
  if (i < 262144){ split_store(P.w2h, P.w2l, i, P.W2[(i&511)*512 + (i>>9)]); return; }  // 512,512
  i -= 262144;
  if (i < 16384){ split_store(P.wvh, P.wvl, i, P.wv[(i&127)*128 + (i>>7)]); return; }   // 128,128
  i -= 16384;
  if (i < 16384){ split_store(P.woh, P.wol, i, P.wo[(i&127)*128 + (i>>7)]); return; }
  i -= 16384;
  if (i < 65536){ split_store(P.f1h, P.f1l, i, P.f1[(i&127)*512 + (i>>7)]); return; }   // 128,512
  i -= 65536;
  if (i < 65536){ split_store(P.f2h, P.f2l, i, P.f2[(i&511)*128 + (i>>9)]); return; }   // 512,128
}

// ---------------- MFMA GEMM: C[MxN] = (Ah+Al) @ (Bh+Bl) with B stored transposed ----------------
static __device__ __forceinline__ short8v ld8(const bf16* p){
  return *(const short8v*)(const void*)(p);
}
template<int K, int SA, int SB, int ACT, int OMODE>
__global__ __launch_bounds__(256) void mgemm(
    const bf16* __restrict__ Ah, const bf16* __restrict__ Al,
    const bf16* __restrict__ Bh, const bf16* __restrict__ Bl,
    const float* __restrict__ bias,
    float* __restrict__ Cf, bf16* __restrict__ Ch, bf16* __restrict__ Cl, int N){
  const int l = threadIdx.x & 63, w = threadIdx.x >> 6;
  const int lg = l >> 4, lr = l & 15;
  const int r0 = (blockIdx.y*4 + w)*64;
  const int c0 = blockIdx.x*64;
  f32x4 acc[4][4] = {};
  int abase[4], bbase[4];
#pragma unroll
  for (int f=0; f<4; f++){
    abase[f] = (r0 + f*16 + lr)*K + lg*8;
    bbase[f] = (c0 + f*16 + lr)*K + lg*8;
  }
#pragma unroll
  for (int k0 = 0; k0 < K; k0 += 32){
    short8v ah[4], alo[4], bh[4], blo[4];
#pragma unroll
    for (int f=0; f<4; f++){
      ah[f] = ld8(Ah + abase[f] + k0);
      if (SA) alo[f] = ld8(Al + abase[f] + k0);
      bh[f] = ld8(Bh + bbase[f] + k0);
      if (SB) blo[f] = ld8(Bl + bbase[f] + k0);
    }
#pragma unroll
    for (int fm=0; fm<4; fm++)
#pragma unroll
      for (int fn=0; fn<4; fn++){
        acc[fm][fn] = __builtin_amdgcn_mfma_f32_16x16x32_bf16(ah[fm], bh[fn], acc[fm][fn], 0,0,0);
        if (SB) acc[fm][fn] = __builtin_amdgcn_mfma_f32_16x16x32_bf16(ah[fm], blo[fn], acc[fm][fn], 0,0,0);
        if (SA) acc[fm][fn] = __builtin_amdgcn_mfma_f32_16x16x32_bf16(alo[fm], bh[fn], acc[fm][fn], 0,0,0);
      }
  }
#pragma unroll
  for (int fm=0; fm<4; fm++){
#pragma unroll
    for (int fn=0; fn<4; fn++){
      const int col = c0 + fn*16 + lr;
      const float bv = bias ? bias[col] : 0.f;
#pragma unroll
      for (int r=0; r<4; r++){
        const int row = r0 + fm*16 + lg*4 + r;
        float v = acc[fm][fn][r] + bv;
        if (ACT==1) v = fmaxf(v, 0.f);
        const size_t idx = (size_t)row*N + col;
        if (OMODE==0) Cf[idx] = v;
        else if (OMODE==1) Ch[idx] = __float2bfloat16(v);
        else split_store(Ch, Cl, idx, v);
      }
    }
  }
}

// ---------------- attention coefficients ----------------
__global__ __launch_bounds__(256) void alsald_kernel(const bf16* __restrict__ h,
    const float* __restrict__ a_s, const float* __restrict__ a_d,
    float* __restrict__ als, float* __restrict__ ald){
  int n = blockIdx.x;
  int w = threadIdx.x >> 6, lane = threadIdx.x & 63;
  int c = w*128 + lane*2;
  bf162 hv = *(const bf162*)&h[(size_t)n*FEAT + c];
  float hx = __bfloat162float(hv.x), hy = __bfloat162float(hv.y);
  float2 as2 = *(const float2*)&a_s[c];
  float2 ad2 = *(const float2*)&a_d[c];
  float s = hx*as2.x + hy*as2.y;
  float d = hx*ad2.x + hy*ad2.y;
#pragma unroll
  for (int o=32;o>0;o>>=1){ s += __shfl_xor(s,o); d += __shfl_xor(d,o); }
  if (lane == 0){ als[n*4+w] = s; ald[n*4+w] = d; }
}

// ---------------- GAT aggregation: 8-way edge-parallel, online softmax + LDS merge ----------------
template<bool CONCAT>
__global__ __launch_bounds__(512) void gat_agg_kernel(const bf16* __restrict__ hfeat,
    const float* __restrict__ als, const float* __restrict__ ald,
    const int* __restrict__ offs, const unsigned short* __restrict__ csr,
    const float* __restrict__ bias, void* __restrict__ outv){
  __shared__ float macc[8][512];
  __shared__ float mm[8][4];
  __shared__ float mden[8][4];
  const int b = blockIdx.x;
  const int n = ((b & 7) << 11) | (b >> 3);   // XCD-cluster swizzle (8 clusters of 2048)
  const int w = threadIdx.x >> 6, l = threadIdx.x & 63, g = l >> 4;
  const float4 ad4 = *(const float4*)&ald[n*4];
  const int beg = offs[n];
  const int cnt = offs[n+1] - beg + 1;        // + implicit self-loop
  float m0=-1e30f,m1=-1e30f,m2=-1e30f,m3=-1e30f;
  float d0=0.f,d1=0.f,d2=0.f,d3=0.f;
  float acc8[8] = {0,0,0,0,0,0,0,0};
  for (int i = w; i < cnt; i += 8){
    const int src = (i < cnt-1) ? (int)csr[beg+i] : n;
    const float4 as4 = *(const float4*)&als[(size_t)src*4];
    float e0 = as4.x + ad4.x; e0 = e0>0.f?e0:0.2f*e0;
    float e1 = as4.y + ad4.y; e1 = e1>0.f?e1:0.2f*e1;
    float e2 = as4.z + ad4.z; e2 = e2>0.f?e2:0.2f*e2;
    float e3 = as4.w + ad4.w; e3 = e3>0.f?e3:0.2f*e3;
    float n0=fmaxf(m0,e0), sc0=__expf(m0-n0), p0=__expf(e0-n0); d0=d0*sc0+p0; m0=n0;
    float n1=fmaxf(m1,e1), sc1=__expf(m1-n1), p1=__expf(e1-n1); d1=d1*sc1+p1; m1=n1;
    float n2=fmaxf(m2,e2), sc2=__expf(m2-n2), p2=__expf(e2-n2); d2=d2*sc2+p2; m2=n2;
    float n3=fmaxf(m3,e3), sc3=__expf(m3-n3), p3=__expf(e3-n3); d3=d3*sc3+p3; m3=n3;
    const float scg = g==0?sc0 : g==1?sc1 : g==2?sc2 : sc3;
    const float pg  = g==0?p0  : g==1?p1  : g==2?p2  : p3;
    const short8v hv = *(const short8v*)(const void*)&hfeat[(size_t)src*FEAT + l*8];
#pragma unroll
    for (int j=0;j<8;j++) acc8[j] = acc8[j]*scg + pg*b2f(hv[j]);
  }
  if (l < 4){
    mm[w][l]   = l==0?m0 : l==1?m1 : l==2?m2 : m3;
    mden[w][l] = l==0?d0 : l==1?d1 : l==2?d2 : d3;
  }
#pragma unroll
  for (int j=0;j<8;j++) macc[w][l*8+j] = acc8[j];
  __syncthreads();
  for (int s=4; s>=1; s>>=1){
    if (w < s){
      const float ma = mm[w][g], mb = mm[w+s][g];
      const float mx = fmaxf(ma,mb);
      const float ea = __expf(ma-mx), eb = __expf(mb-mx);
      float va[8];
#pragma unroll
      for (int j=0;j<8;j++) va[j] = macc[w][l*8+j]*ea + macc[w+s][l*8+j]*eb;
      float nm=0.f, nd=0.f;
      if (l < 4){
        const float A = mm[w][l], B = mm[w+s][l];
        nm = fmaxf(A,B);
        nd = mden[w][l]*__expf(A-nm) + mden[w+s][l]*__expf(B-nm);
      }
#pragma unroll
      for (int j=0;j<8;j++) macc[w][l*8+j] = va[j];
      if (l < 4){ mm[w][l] = nm; mden[w][l] = nd; }
    }
    __syncthreads();
  }
  if (CONCAT){
    if (w == 0){
      const float inv = 1.f/(mden[0][g] + 1e-16f);
      short8v ov;
#pragma unroll
      for (int j=0;j<8;j++){
        float v = macc[0][l*8+j]*inv + bias[l*8+j];
        v = v > 0.f ? v : expm1f(v);            // fused ELU
        bf16 bv = __float2bfloat16(v);
        ov[j] = (short)*(unsigned short*)&bv;
      }
      *(short8v*)((char*)outv + ((size_t)n*FEAT + l*8)*2) = ov;
    }
  } else {
    if (threadIdx.x < 128){
      const int j = threadIdx.x;
      float sum = 0.f;
#pragma unroll
      for (int h=0; h<4; h++) sum += macc[0][h*128+j] / (mden[0][h] + 1e-16f);
      ((float*)outv)[(size_t)n*128 + j] = 0.25f*sum + bias[j];
    }
  }
}

// ---------------- q = h2 + pe[L-1] (in place) + bf16 split ----------------
__global__ void add_pe_kernel(float* __restrict__ h2, bf16* __restrict__ qh, bf16* __restrict__ ql, int total){
  int i = blockIdx.x*blockDim.x + threadIdx.x;
  if (i < total){
    int j = i & 127;
    float ex = __expf((float)(j & ~1) * (-9.210340371976184f/128.f));
    float pe = (j & 1) ? cosf(4.f*ex) : sinf(4.f*ex);
    float v = h2[i] + pe;
    h2[i] = v;
    split_store(qh, ql, i, v);
  }
}

// ---------------- LayerNorm(a+b), optional bf16 split output ----------------
template<int SPLIT>
__global__ __launch_bounds__(256) void ln_kernel(const float* __restrict__ a, const float* __restrict__ b,
    const float* __restrict__ g, const float* __restrict__ bb, float* __restrict__ out,
    bf16* __restrict__ oh, bf16* __restrict__ ol){
  int row = blockIdx.x*4 + (threadIdx.x >> 6);
  int lane = threadIdx.x & 63;
  int c = lane*2;
  float2 va = *(const float2*)&a[(size_t)row*128 + c];
  float2 vb = *(const float2*)&b[(size_t)row*128 + c];
  float x0 = va.x+vb.x, x1 = va.y+vb.y;
  float s = x0+x1, q = x0*x0 + x1*x1;
#pragma unroll
  for (int o=32;o>0;o>>=1){ s += __shfl_xor(s,o); q += __shfl_xor(q,o); }
  float mu = s*(1.f/128.f);
  float var = q*(1.f/128.f) - mu*mu;
  float r = 1.f/sqrtf(var + 1e-5f);
  float y0 = (x0-mu)*r*g[c]   + bb[c];
  float y1 = (x1-mu)*r*g[c+1] + bb[c+1];
  size_t idx = (size_t)row*128 + c;
  out[idx] = y0; out[idx+1] = y1;
  if (SPLIT){ split_store(oh, ol, idx, y0); split_store(oh, ol, idx+1, y1); }
}

// ---------------- final: out = y @ wc(128x2) + bc ----------------
__global__ __launch_bounds__(256) void final_kernel(const float* __restrict__ y,
    const float* __restrict__ wc, const float* __restrict__ bc,
    float* __restrict__ out){
  int row = blockIdx.x*4 + (threadIdx.x >> 6);
  int lane = threadIdx.x & 63;
  int k = lane*2;
  float2 v = *(const float2*)&y[(size_t)row*128 + k];
  float s0 = v.x*wc[k*2]   + v.y*wc[(k+1)*2];
  float s1 = v.x*wc[k*2+1] + v.y*wc[(k+1)*2+1];
#pragma unroll
  for (int o=32;o>0;o>>=1){ s0 += __shfl_xor(s0,o); s1 += __shfl_xor(s1,o); }
  if (lane == 0){
    out[row*2]   = s0 + bc[0];
    out[row*2+1] = s1 + bc[1];
  }
}

extern "C" void kernel_launch(void* const* d_in, const int* in_sizes, int n_in,
                              void* d_out, int out_size, void* d_ws, size_t ws_size,
                              hipStream_t stream){
  const float* x      = (const float*)d_in[0];
  const int*   ei     = (const int*)d_in[1];
  const float* W1     = (const float*)d_in[3];
  const float* a_src1 = (const float*)d_in[4];
  const float* a_dst1 = (const float*)d_in[5];
  const float* b1     = (const float*)d_in[6];
  const float* W2     = (const float*)d_in[7];
  const float* a_src2 = (const float*)d_in[8];
  const float* a_dst2 = (const float*)d_in[9];
  const float* b2     = (const float*)d_in[10];
  const float* wv     = (const float*)d_in[15];
  const float* bv     = (const float*)d_in[16];
  const float* wo     = (const float*)d_in[17];
  const float* bo     = (const float*)d_in[18];
  const float* ln_g   = (const float*)d_in[19];
  const float* ln_b   = (const float*)d_in[20];
  const float* f1     = (const float*)d_in[21];
  const float* fb1    = (const float*)d_in[22];
  const float* f2     = (const float*)d_in[23];
  const float* fb2    = (const float*)d_in[24];
  const float* wc     = (const float*)d_in[25];
  const float* bc     = (const float*)d_in[26];
  float* outp = (float*)d_out;

  const int E = in_sizes[1] / 2;
  const int n = NODES;
  const int tE = 2*E;
  const size_t MB = 1024*1024;

  const size_t NEED = 36*MB;
  if (ws_size < NEED){
    sentinel_kernel<<<(out_size+255)/256, 256, 0, stream>>>(outp, out_size,
        1000.0f + (float)(ws_size / MB));
    return;
  }

  // ---- arena [0,36) MB; tail liveness audited phase-by-phase ----
  char* base = (char*)d_ws;
  bf16*  h1    = (bf16*)(base + 0);          // [0,16): gemm1 out
  bf16*  xh    = (bf16*)(base + 16*MB);      // [16,20)
  bf16*  xl    = (bf16*)(base + 20*MB);      // [20,24)
  bf16*  h     = (bf16*)(base + 16*MB);      // [16,32): agg1 out (xh/xl dead)
  bf16*  h2f   = (bf16*)(base + 0);          // [0,16): gemm2 out (h1 dead)
  float* h2q   = (float*)(base + 16*MB);     // [16,24): agg2 out f32 (h dead)
  bf16*  qh    = (bf16*)(base + 24*MB);      // [24,28)
  bf16*  ql    = (bf16*)(base + 28*MB);      // [28,32)
  bf16*  vh    = (bf16*)(base + 0);          // [0,4)   (h2f dead)
  bf16*  vl    = (bf16*)(base + 4*MB);       // [4,8)
  float* aobuf = (float*)(base + 8*MB);      // [8,16)
  float* y1    = (float*)(base + 24*MB);     // [24,32) (qh/ql dead)
  bf16*  y1h   = (bf16*)(base + 0);          // [0,4)   (vh/vl dead)
  bf16*  y1l   = (bf16*)(base + 4*MB);       // [4,8)
  bf16*  hidden= (bf16*)(base + 8*MB);       // [8,24) 16MB! N*512 bf16 (aobuf,h2q dead)
  float* ffn2f = (float*)(base + 0);         // [0,8)   (y1h/l dead after ffn1)
  float* y2    = (float*)(base + 8*MB);      // [8,16)  (hidden dead after ffn2)
  // small arrays
  char* u = base + 32*MB;
  bf16* w1h = (bf16*)u; u += 131072;  bf16* w1l = (bf16*)u; u += 131072;
  bf16* w2h = (bf16*)u; u += 524288;  bf16* w2l = (bf16*)u; u += 524288;
  bf16* wvh = (bf16*)u; u += 32768;   bf16* wvl = (bf16*)u; u += 32768;
  bf16* woh = (bf16*)u; u += 32768;   bf16* wol = (bf16*)u; u += 32768;
  bf16* f1h = (bf16*)u; u += 131072;  bf16* f1l = (bf16*)u; u += 131072;
  bf16* f2h = (bf16*)u; u += 131072;  bf16* f2l = (bf16*)u; u += 131072;
  float* als = (float*)u; u += (size_t)n*4*4;
  float* ald = (float*)u; u += (size_t)n*4*4;
  int* counts = (int*)u; u += (size_t)n*4;
  int* offs   = (int*)u; u += (size_t)(n+1)*4 + 252;
  int* cursor = (int*)u; u += (size_t)n*4;
  unsigned short* csr = (unsigned short*)u; u += (size_t)tE*2;

  // ---- prep + CSR ----
  PrepArgs P = { x,W1,W2,wv,wo,f1,f2, xh,xl,w1h,w1l,w2h,w2l,wvh,wvl,woh,wol,f1h,f1l,f2h,f2l };
  prep_kernel<<<(2588672+255)/256, 256, 0, stream>>>(P);
  zero_kernel<<<(n+255)/256, 256, 0, stream>>>(counts, n);
  count_kernel<<<(tE+255)/256, 256, 0, stream>>>(ei, counts, E);
  scan_kernel<<<1, 1024, 0, stream>>>(counts, offs, cursor);
  fill_kernel<<<(tE+255)/256, 256, 0, stream>>>(ei, cursor, csr, E);

  // ---- GAT layer 1 ----
  mgemm<128,1,1,0,1><<<dim3(8,64), 256, 0, stream>>>(xh, xl, w1h, w1l, nullptr, nullptr, h1, nullptr, 512);
  alsald_kernel<<<n, 256, 0, stream>>>(h1, a_src1, a_dst1, als, ald);
  gat_agg_kernel<true><<<n, 512, 0, stream>>>(h1, als, ald, offs, csr, b1, h);

  // ---- GAT layer 2 ----
  mgemm<512,0,1,0,1><<<dim3(8,64), 256, 0, stream>>>(h, nullptr, w2h, w2l, nullptr, nullptr, h2f, nullptr, 512);
  alsald_kernel<<<n, 256, 0, stream>>>(h2f, a_src2, a_dst2, als, ald);
  gat_agg_kernel<false><<<n, 512, 0, stream>>>(h2f, als, ald, offs, csr, b2, h2q);

  // ---- temporal attention (collapsed to V at l=L-1) + head ----
  add_pe_kernel<<<(n*128+255)/256, 256, 0, stream>>>(h2q, qh, ql, n*128);
  mgemm<128,1,1,0,2><<<dim3(2,64), 256, 0, stream>>>(qh, ql, wvh, wvl, bv, nullptr, vh, vl, 128);
  mgemm<128,1,1,0,0><<<dim3(2,64), 256, 0, stream>>>(vh, vl, woh, wol, bo, aobuf, nullptr, nullptr, 128);
  ln_kernel<1><<<n/4, 256, 0, stream>>>(h2q, aobuf, ln_g, ln_b, y1, y1h, y1l);
  mgemm<128,1,1,1,1><<<dim3(8,64), 256, 0, stream>>>(y1h, y1l, f1h, f1l, fb1, nullptr, hidden, nullptr, 512);
  mgemm<512,0,1,0,0><<<dim3(2,64), 256, 0, stream>>>(hidden, nullptr, f2h, f2l, fb2, ffn2f, nullptr, nullptr, 128);
  ln_kernel<0><<<n/4, 256, 0, stream>>>(y1, ffn2f, ln_g, ln_b, y2, nullptr, nullptr);
  final_kernel<<<n/4, 256, 0, stream>>>(y2, wc, bc, outp);
}

// Round 9
// 394.795 us; speedup vs baseline: 1.8349x; 1.2323x over previous
//
#include <hip/hip_runtime.h>
#include <hip/hip_bf16.h>

#define NODES 16384
#define FEAT 512
typedef __hip_bfloat16 bf16;
typedef __hip_bfloat162 bf162;
typedef short short8v __attribute__((ext_vector_type(8)));
typedef float f32x4 __attribute__((ext_vector_type(4)));

static __device__ __forceinline__ float b2f(short s){
  return __uint_as_float(((unsigned)(unsigned short)s) << 16);
}
static __device__ __forceinline__ void split_store(bf16* h, bf16* l, size_t i, float v){
  bf16 hi = __float2bfloat16(v);
  h[i] = hi; l[i] = __float2bfloat16(v - __bfloat162float(hi));
}

// ---------------- diagnostic sentinel ----------------
__global__ void sentinel_kernel(float* __restrict__ out, int n, float v){
  int i = blockIdx.x*blockDim.x + threadIdx.x;
  if (i < n) out[i] = v;
}

// ---------------- CSR build ----------------
__global__ void zero_kernel(int* __restrict__ p, int n){
  int i = blockIdx.x*blockDim.x + threadIdx.x;
  if (i < n) p[i] = 0;
}
__global__ void count_kernel(const int* __restrict__ ei, int* __restrict__ counts, int E){
  int i = blockIdx.x*blockDim.x + threadIdx.x;
  if (i < 2*E){
    int dst = (i < E) ? ei[E+i] : ei[i-E];
    atomicAdd(&counts[dst], 1);
  }
}
__global__ __launch_bounds__(1024) void scan_kernel(const int* __restrict__ counts,
                                                    int* __restrict__ offs, int* __restrict__ cursor){
  __shared__ int sh[1024];
  const int t = threadIdx.x;
  int loc[16]; int s = 0;
#pragma unroll
  for (int i=0;i<16;i++){ loc[i] = counts[t*16+i]; s += loc[i]; }
  sh[t] = s; __syncthreads();
  for (int d=1; d<1024; d<<=1){
    int v = (t>=d) ? sh[t-d] : 0;
    __syncthreads(); sh[t] += v; __syncthreads();
  }
  int run = (t==0) ? 0 : sh[t-1];
#pragma unroll
  for (int i=0;i<16;i++){ offs[t*16+i] = run; cursor[t*16+i] = run; run += loc[i]; }
  if (t==1023) offs[NODES] = run;
}
__global__ void fill_kernel(const int* __restrict__ ei, int* __restrict__ cursor,
                            unsigned short* __restrict__ csr, int E){
  int i = blockIdx.x*blockDim.x + threadIdx.x;
  if (i < 2*E){
    int src = ei[i];
    int dst = (i < E) ? ei[E+i] : ei[i-E];
    int pos = atomicAdd(&cursor[dst], 1);
    csr[pos] = (unsigned short)src;
  }
}

// ---------------- prep: split x + transpose/split all weights to bf16 pairs ----------------
struct PrepArgs {
  const float *x,*W1,*W2,*wv,*wo,*f1,*f2;
  bf16 *xh,*xl,*w1h,*w1l,*w2h,*w2l,*wvh,*wvl,*woh,*wol,*f1h,*f1l,*f2h,*f2l;
};
__global__ void prep_kernel(PrepArgs P){
  int i = blockIdx.x*blockDim.x + threadIdx.x;
  if (i < 2097152){ split_store(P.xh, P.xl, i, P.x[i]); return; }
  i -= 2097152;
  if (i < 65536){ split_store(P.w1h, P.w1l, i, P.W1[(i&127)*512 + (i>>7)]); return; }   // K=128,N=512
  i -= 65536;
  if (i < 262144){ split_store(P.w2h, P.w2l, i, P.W2[(i&511)*512 + (i>>9)]); return; }  // 512,512
  i -= 262144;
  if (i < 16384){ split_store(P.wvh, P.wvl, i, P.wv[(i&127)*128 + (i>>7)]); return; }   // 128,128
  i -= 16384;
  if (i < 16384){ split_store(P.woh, P.wol, i, P.wo[(i&127)*128 + (i>>7)]); return; }
  i -= 16384;
  if (i < 65536){ split_store(P.f1h, P.f1l, i, P.f1[(i&127)*512 + (i>>7)]); return; }   // 128,512
  i -= 65536;
  if (i < 65536){ split_store(P.f2h, P.f2l, i, P.f2[(i&511)*128 + (i>>9)]); return; }   // 512,128
}

// ---------------- MFMA GEMM: C[MxN] = (Ah+Al) @ (Bh+Bl) with B stored transposed ----------------
static __device__ __forceinline__ short8v ld8(const bf16* p){
  return *(const short8v*)(const void*)(p);
}
template<int K, int SA, int SB, int ACT, int OMODE>
__global__ __launch_bounds__(256) void mgemm(
    const bf16* __restrict__ Ah, const bf16* __restrict__ Al,
    const bf16* __restrict__ Bh, const bf16* __restrict__ Bl,
    const float* __restrict__ bias,
    float* __restrict__ Cf, bf16* __restrict__ Ch, bf16* __restrict__ Cl, int N){
  const int l = threadIdx.x & 63, w = threadIdx.x >> 6;
  const int lg = l >> 4, lr = l & 15;
  const int r0 = (blockIdx.y*4 + w)*64;
  const int c0 = blockIdx.x*64;
  f32x4 acc[4][4] = {};
  int abase[4], bbase[4];
#pragma unroll
  for (int f=0; f<4; f++){
    abase[f] = (r0 + f*16 + lr)*K + lg*8;
    bbase[f] = (c0 + f*16 + lr)*K + lg*8;
  }
#pragma unroll
  for (int k0 = 0; k0 < K; k0 += 32){
    short8v ah[4], alo[4], bh[4], blo[4];
#pragma unroll
    for (int f=0; f<4; f++){
      ah[f] = ld8(Ah + abase[f] + k0);
      if (SA) alo[f] = ld8(Al + abase[f] + k0);
      bh[f] = ld8(Bh + bbase[f] + k0);
      if (SB) blo[f] = ld8(Bl + bbase[f] + k0);
    }
#pragma unroll
    for (int fm=0; fm<4; fm++)
#pragma unroll
      for (int fn=0; fn<4; fn++){
        acc[fm][fn] = __builtin_amdgcn_mfma_f32_16x16x32_bf16(ah[fm], bh[fn], acc[fm][fn], 0,0,0);
        if (SB) acc[fm][fn] = __builtin_amdgcn_mfma_f32_16x16x32_bf16(ah[fm], blo[fn], acc[fm][fn], 0,0,0);
        if (SA) acc[fm][fn] = __builtin_amdgcn_mfma_f32_16x16x32_bf16(alo[fm], bh[fn], acc[fm][fn], 0,0,0);
      }
  }
#pragma unroll
  for (int fm=0; fm<4; fm++){
#pragma unroll
    for (int fn=0; fn<4; fn++){
      const int col = c0 + fn*16 + lr;
      const float bv = bias ? bias[col] : 0.f;
#pragma unroll
      for (int r=0; r<4; r++){
        const int row = r0 + fm*16 + lg*4 + r;
        float v = acc[fm][fn][r] + bv;
        if (ACT==1) v = fmaxf(v, 0.f);
        const size_t idx = (size_t)row*N + col;
        if (OMODE==0) Cf[idx] = v;
        else if (OMODE==1) Ch[idx] = __float2bfloat16(v);
        else split_store(Ch, Cl, idx, v);
      }
    }
  }
}

// ---------------- attention coefficients ----------------
__global__ __launch_bounds__(256) void alsald_kernel(const bf16* __restrict__ h,
    const float* __restrict__ a_s, const float* __restrict__ a_d,
    float* __restrict__ als, float* __restrict__ ald){
  int n = blockIdx.x;
  int w = threadIdx.x >> 6, lane = threadIdx.x & 63;
  int c = w*128 + lane*2;
  bf162 hv = *(const bf162*)&h[(size_t)n*FEAT + c];
  float hx = __bfloat162float(hv.x), hy = __bfloat162float(hv.y);
  float2 as2 = *(const float2*)&a_s[c];
  float2 ad2 = *(const float2*)&a_d[c];
  float s = hx*as2.x + hy*as2.y;
  float d = hx*ad2.x + hy*ad2.y;
#pragma unroll
  for (int o=32;o>0;o>>=1){ s += __shfl_xor(s,o); d += __shfl_xor(d,o); }
  if (lane == 0){ als[n*4+w] = s; ald[n*4+w] = d; }
}

// ---------------- Phase A: per (node,head) fused softmax scalar C = exp(-m)/(den+1e-16) ----------------
__global__ __launch_bounds__(256) void softmax_prep_kernel(
    const float* __restrict__ als, const float* __restrict__ ald,
    const int* __restrict__ offs, const unsigned short* __restrict__ csr,
    float* __restrict__ Carr){
  const int w = threadIdx.x >> 6, l = threadIdx.x & 63;
  const int nb = blockIdx.x;
  const int n = (nb & 7)*2048 + (nb >> 3)*4 + w;   // cluster-contiguous, XCD-aligned
  const float4 ad4 = *(const float4*)&ald[(size_t)n*4];
  const int beg = offs[n];
  const int cnt = offs[n+1] - beg + 1;             // + implicit self-loop
  float m0=-1e30f,m1=-1e30f,m2=-1e30f,m3=-1e30f;
  float d0=0.f,d1=0.f,d2=0.f,d3=0.f;
  for (int i = l; i < cnt; i += 64){
    const int src = (i < cnt-1) ? (int)csr[beg+i] : n;
    const float4 as4 = *(const float4*)&als[(size_t)src*4];
    float e0 = as4.x + ad4.x; e0 = e0>0.f?e0:0.2f*e0;
    float e1 = as4.y + ad4.y; e1 = e1>0.f?e1:0.2f*e1;
    float e2 = as4.z + ad4.z; e2 = e2>0.f?e2:0.2f*e2;
    float e3 = as4.w + ad4.w; e3 = e3>0.f?e3:0.2f*e3;
    float n0=fmaxf(m0,e0); d0=d0*__expf(m0-n0)+__expf(e0-n0); m0=n0;
    float n1=fmaxf(m1,e1); d1=d1*__expf(m1-n1)+__expf(e1-n1); m1=n1;
    float n2=fmaxf(m2,e2); d2=d2*__expf(m2-n2)+__expf(e2-n2); m2=n2;
    float n3=fmaxf(m3,e3); d3=d3*__expf(m3-n3)+__expf(e3-n3); m3=n3;
  }
#pragma unroll
  for (int o=32;o>0;o>>=1){
    float mo, dd, nm;
    mo=__shfl_xor(m0,o); dd=__shfl_xor(d0,o); nm=fmaxf(m0,mo);
    d0=d0*__expf(m0-nm)+dd*__expf(mo-nm); m0=nm;
    mo=__shfl_xor(m1,o); dd=__shfl_xor(d1,o); nm=fmaxf(m1,mo);
    d1=d1*__expf(m1-nm)+dd*__expf(mo-nm); m1=nm;
    mo=__shfl_xor(m2,o); dd=__shfl_xor(d2,o); nm=fmaxf(m2,mo);
    d2=d2*__expf(m2-nm)+dd*__expf(mo-nm); m2=nm;
    mo=__shfl_xor(m3,o); dd=__shfl_xor(d3,o); nm=fmaxf(m3,mo);
    d3=d3*__expf(m3-nm)+dd*__expf(mo-nm); m3=nm;
  }
  if (l == 0){
    float4 c4;
    c4.x = __expf(-m0)/(d0+1e-16f);
    c4.y = __expf(-m1)/(d1+1e-16f);
    c4.z = __expf(-m2)/(d2+1e-16f);
    c4.w = __expf(-m3)/(d3+1e-16f);
    *(float4*)&Carr[(size_t)n*4] = c4;
  }
}

// ---------------- Phase B: one wave per node, alpha = exp(e)*C, no LDS ----------------
template<bool CONCAT>
__global__ __launch_bounds__(256) void gat_agg2_kernel(const bf16* __restrict__ hfeat,
    const float* __restrict__ als, const float* __restrict__ ald,
    const float* __restrict__ Carr, const int* __restrict__ offs,
    const unsigned short* __restrict__ csr, const float* __restrict__ bias,
    void* __restrict__ outv){
  const int w = threadIdx.x >> 6, l = threadIdx.x & 63, g = l >> 4;
  const int nb = blockIdx.x;
  const int n = (nb & 7)*2048 + (nb >> 3)*4 + w;   // cluster-contiguous, XCD-aligned
  const float adg = ald[(size_t)n*4 + g];
  const float Cg  = Carr[(size_t)n*4 + g];
  const int beg = offs[n];
  const int cnt = offs[n+1] - beg + 1;
  float acc[8] = {0,0,0,0,0,0,0,0};
  for (int i = 0; i < cnt; ++i){
    const int src = (i < cnt-1) ? (int)csr[beg+i] : n;
    float e = als[(size_t)src*4 + g] + adg;
    e = e > 0.f ? e : 0.2f*e;
    const float a = __expf(e) * Cg;
    const short8v hv = *(const short8v*)(const void*)&hfeat[(size_t)src*FEAT + l*8];
#pragma unroll
    for (int j=0;j<8;j++) acc[j] += a * b2f(hv[j]);
  }
  if (CONCAT){
    short8v ov;
#pragma unroll
    for (int j=0;j<8;j++){
      float v = acc[j] + bias[l*8+j];
      v = v > 0.f ? v : expm1f(v);               // fused ELU
      bf16 bv = __float2bfloat16(v);
      ov[j] = (short)*(unsigned short*)&bv;
    }
    *(short8v*)((char*)outv + ((size_t)n*FEAT + l*8)*2) = ov;
  } else {
#pragma unroll
    for (int j=0;j<8;j++){
      acc[j] += __shfl_xor(acc[j], 16);
      acc[j] += __shfl_xor(acc[j], 32);
    }
    if (l < 16){
      float* op = (float*)outv + (size_t)n*128 + l*8;
#pragma unroll
      for (int j=0;j<8;j++) op[j] = 0.25f*acc[j] + bias[l*8+j];
    }
  }
}

// ---------------- q = h2 + pe[L-1] (in place) + bf16 split ----------------
__global__ void add_pe_kernel(float* __restrict__ h2, bf16* __restrict__ qh, bf16* __restrict__ ql, int total){
  int i = blockIdx.x*blockDim.x + threadIdx.x;
  if (i < total){
    int j = i & 127;
    float ex = __expf((float)(j & ~1) * (-9.210340371976184f/128.f));
    float pe = (j & 1) ? cosf(4.f*ex) : sinf(4.f*ex);
    float v = h2[i] + pe;
    h2[i] = v;
    split_store(qh, ql, i, v);
  }
}

// ---------------- LayerNorm(a+b), optional bf16 split output ----------------
template<int SPLIT>
__global__ __launch_bounds__(256) void ln_kernel(const float* __restrict__ a, const float* __restrict__ b,
    const float* __restrict__ g, const float* __restrict__ bb, float* __restrict__ out,
    bf16* __restrict__ oh, bf16* __restrict__ ol){
  int row = blockIdx.x*4 + (threadIdx.x >> 6);
  int lane = threadIdx.x & 63;
  int c = lane*2;
  float2 va = *(const float2*)&a[(size_t)row*128 + c];
  float2 vb = *(const float2*)&b[(size_t)row*128 + c];
  float x0 = va.x+vb.x, x1 = va.y+vb.y;
  float s = x0+x1, q = x0*x0 + x1*x1;
#pragma unroll
  for (int o=32;o>0;o>>=1){ s += __shfl_xor(s,o); q += __shfl_xor(q,o); }
  float mu = s*(1.f/128.f);
  float var = q*(1.f/128.f) - mu*mu;
  float r = 1.f/sqrtf(var + 1e-5f);
  float y0 = (x0-mu)*r*g[c]   + bb[c];
  float y1 = (x1-mu)*r*g[c+1] + bb[c+1];
  size_t idx = (size_t)row*128 + c;
  out[idx] = y0; out[idx+1] = y1;
  if (SPLIT){ split_store(oh, ol, idx, y0); split_store(oh, ol, idx+1, y1); }
}

// ---------------- final: out = y @ wc(128x2) + bc ----------------
__global__ __launch_bounds__(256) void final_kernel(const float* __restrict__ y,
    const float* __restrict__ wc, const float* __restrict__ bc,
    float* __restrict__ out){
  int row = blockIdx.x*4 + (threadIdx.x >> 6);
  int lane = threadIdx.x & 63;
  int k = lane*2;
  float2 v = *(const float2*)&y[(size_t)row*128 + k];
  float s0 = v.x*wc[k*2]   + v.y*wc[(k+1)*2];
  float s1 = v.x*wc[k*2+1] + v.y*wc[(k+1)*2+1];
#pragma unroll
  for (int o=32;o>0;o>>=1){ s0 += __shfl_xor(s0,o); s1 += __shfl_xor(s1,o); }
  if (lane == 0){
    out[row*2]   = s0 + bc[0];
    out[row*2+1] = s1 + bc[1];
  }
}

extern "C" void kernel_launch(void* const* d_in, const int* in_sizes, int n_in,
                              void* d_out, int out_size, void* d_ws, size_t ws_size,
                              hipStream_t stream){
  const float* x      = (const float*)d_in[0];
  const int*   ei     = (const int*)d_in[1];
  const float* W1     = (const float*)d_in[3];
  const float* a_src1 = (const float*)d_in[4];
  const float* a_dst1 = (const float*)d_in[5];
  const float* b1     = (const float*)d_in[6];
  const float* W2     = (const float*)d_in[7];
  const float* a_src2 = (const float*)d_in[8];
  const float* a_dst2 = (const float*)d_in[9];
  const float* b2     = (const float*)d_in[10];
  const float* wv     = (const float*)d_in[15];
  const float* bv     = (const float*)d_in[16];
  const float* wo     = (const float*)d_in[17];
  const float* bo     = (const float*)d_in[18];
  const float* ln_g   = (const float*)d_in[19];
  const float* ln_b   = (const float*)d_in[20];
  const float* f1     = (const float*)d_in[21];
  const float* fb1    = (const float*)d_in[22];
  const float* f2     = (const float*)d_in[23];
  const float* fb2    = (const float*)d_in[24];
  const float* wc     = (const float*)d_in[25];
  const float* bc     = (const float*)d_in[26];
  float* outp = (float*)d_out;

  const int E = in_sizes[1] / 2;
  const int n = NODES;
  const int tE = 2*E;
  const size_t MB = 1024*1024;

  const size_t NEED = 36*MB;
  if (ws_size < NEED){
    sentinel_kernel<<<(out_size+255)/256, 256, 0, stream>>>(outp, out_size,
        1000.0f + (float)(ws_size / MB));
    return;
  }

  // ---- arena [0,36) MB; liveness audited phase-by-phase ----
  char* base = (char*)d_ws;
  // CSR-build temporaries live BEFORE gemm1 writes h1:
  int* counts = (int*)(base + 0);            // [0,64K)
  int* cursor = (int*)(base + 65536);        // [64K,128K)
  bf16*  h1    = (bf16*)(base + 0);          // [0,16): gemm1 out (after CSR build)
  bf16*  xh    = (bf16*)(base + 16*MB);      // [16,20)
  bf16*  xl    = (bf16*)(base + 20*MB);      // [20,24)
  bf16*  h     = (bf16*)(base + 16*MB);      // [16,32): agg1 out (xh/xl dead)
  bf16*  h2f   = (bf16*)(base + 0);          // [0,16): gemm2 out (h1 dead)
  float* h2q   = (float*)(base + 16*MB);     // [16,24): agg2 out f32 (h dead)
  bf16*  qh    = (bf16*)(base + 24*MB);      // [24,28)
  bf16*  ql    = (bf16*)(base + 28*MB);      // [28,32)
  bf16*  vh    = (bf16*)(base + 0);          // [0,4)   (h2f dead)
  bf16*  vl    = (bf16*)(base + 4*MB);       // [4,8)
  float* aobuf = (float*)(base + 8*MB);      // [8,16)
  float* y1    = (float*)(base + 24*MB);     // [24,32) (qh/ql dead)
  bf16*  y1h   = (bf16*)(base + 0);          // [0,4)   (vh/vl dead)
  bf16*  y1l   = (bf16*)(base + 4*MB);       // [4,8)
  bf16*  hidden= (bf16*)(base + 8*MB);       // [8,24) 16MB N*512 bf16 (aobuf,h2q dead)
  float* ffn2f = (float*)(base + 0);         // [0,8)   (y1h/l dead after ffn1)
  float* y2    = (float*)(base + 8*MB);      // [8,16)  (hidden dead after ffn2)
  // S region [32,36)
  char* u = base + 32*MB;
  bf16* w1h = (bf16*)u; u += 131072;  bf16* w1l = (bf16*)u; u += 131072;
  bf16* w2h = (bf16*)u; u += 524288;  bf16* w2l = (bf16*)u; u += 524288;
  bf16* wvh = (bf16*)u; u += 32768;   bf16* wvl = (bf16*)u; u += 32768;
  bf16* woh = (bf16*)u; u += 32768;   bf16* wol = (bf16*)u; u += 32768;
  bf16* f1h = (bf16*)u; u += 131072;  bf16* f1l = (bf16*)u; u += 131072;
  bf16* f2h = (bf16*)u; u += 131072;  bf16* f2l = (bf16*)u; u += 131072;
  float* als  = (float*)u; u += (size_t)n*4*4;
  float* ald  = (float*)u; u += (size_t)n*4*4;
  float* Carr = (float*)u; u += (size_t)n*4*4;
  int* offs   = (int*)u;   u += (size_t)(n+1)*4 + 252;
  unsigned short* csr = (unsigned short*)u; u += (size_t)tE*2;

  // ---- prep + CSR ----
  PrepArgs P = { x,W1,W2,wv,wo,f1,f2, xh,xl,w1h,w1l,w2h,w2l,wvh,wvl,woh,wol,f1h,f1l,f2h,f2l };
  prep_kernel<<<(2588672+255)/256, 256, 0, stream>>>(P);
  zero_kernel<<<(n+255)/256, 256, 0, stream>>>(counts, n);
  count_kernel<<<(tE+255)/256, 256, 0, stream>>>(ei, counts, E);
  scan_kernel<<<1, 1024, 0, stream>>>(counts, offs, cursor);
  fill_kernel<<<(tE+255)/256, 256, 0, stream>>>(ei, cursor, csr, E);

  // ---- GAT layer 1 ----
  mgemm<128,1,1,0,1><<<dim3(8,64), 256, 0, stream>>>(xh, xl, w1h, w1l, nullptr, nullptr, h1, nullptr, 512);
  alsald_kernel<<<n, 256, 0, stream>>>(h1, a_src1, a_dst1, als, ald);
  softmax_prep_kernel<<<n/4, 256, 0, stream>>>(als, ald, offs, csr, Carr);
  gat_agg2_kernel<true><<<n/4, 256, 0, stream>>>(h1, als, ald, Carr, offs, csr, b1, h);

  // ---- GAT layer 2 ----
  mgemm<512,0,1,0,1><<<dim3(8,64), 256, 0, stream>>>(h, nullptr, w2h, w2l, nullptr, nullptr, h2f, nullptr, 512);
  alsald_kernel<<<n, 256, 0, stream>>>(h2f, a_src2, a_dst2, als, ald);
  softmax_prep_kernel<<<n/4, 256, 0, stream>>>(als, ald, offs, csr, Carr);
  gat_agg2_kernel<false><<<n/4, 256, 0, stream>>>(h2f, als, ald, Carr, offs, csr, b2, h2q);

  // ---- temporal attention (collapsed to V at l=L-1) + head ----
  add_pe_kernel<<<(n*128+255)/256, 256, 0, stream>>>(h2q, qh, ql, n*128);
  mgemm<128,1,1,0,2><<<dim3(2,64), 256, 0, stream>>>(qh, ql, wvh, wvl, bv, nullptr, vh, vl, 128);
  mgemm<128,1,1,0,0><<<dim3(2,64), 256, 0, stream>>>(vh, vl, woh, wol, bo, aobuf, nullptr, nullptr, 128);
  ln_kernel<1><<<n/4, 256, 0, stream>>>(h2q, aobuf, ln_g, ln_b, y1, y1h, y1l);
  mgemm<128,1,1,1,1><<<dim3(8,64), 256, 0, stream>>>(y1h, y1l, f1h, f1l, fb1, nullptr, hidden, nullptr, 512);
  mgemm<512,0,1,0,0><<<dim3(2,64), 256, 0, stream>>>(hidden, nullptr, f2h, f2l, fb2, ffn2f, nullptr, nullptr, 128);
  ln_kernel<0><<<n/4, 256, 0, stream>>>(y1, ffn2f, ln_g, ln_b, y2, nullptr, nullptr);
  final_kernel<<<n/4, 256, 0, stream>>>(y2, wc, bc, outp);
}

// Round 10
// 356.919 us; speedup vs baseline: 2.0296x; 1.1061x over previous
//
#include <hip/hip_runtime.h>
#include <hip/hip_bf16.h>

#define NODES 16384
#define FEAT 512
typedef __hip_bfloat16 bf16;
typedef __hip_bfloat162 bf162;
typedef short short8v __attribute__((ext_vector_type(8)));
typedef float f32x4 __attribute__((ext_vector_type(4)));

static __device__ __forceinline__ float b2f(short s){
  return __uint_as_float(((unsigned)(unsigned short)s) << 16);
}
static __device__ __forceinline__ void split_store(bf16* h, bf16* l, size_t i, float v){
  bf16 hi = __float2bfloat16(v);
  h[i] = hi; l[i] = __float2bfloat16(v - __bfloat162float(hi));
}

// ---------------- diagnostic sentinel ----------------
__global__ void sentinel_kernel(float* __restrict__ out, int n, float v){
  int i = blockIdx.x*blockDim.x + threadIdx.x;
  if (i < n) out[i] = v;
}

// ---------------- CSR build ----------------
__global__ void zero_kernel(int* __restrict__ p, int n){
  int i = blockIdx.x*blockDim.x + threadIdx.x;
  if (i < n) p[i] = 0;
}
__global__ void count_kernel(const int* __restrict__ ei, int* __restrict__ counts, int E){
  int i = blockIdx.x*blockDim.x + threadIdx.x;
  if (i < 2*E){
    int dst = (i < E) ? ei[E+i] : ei[i-E];
    atomicAdd(&counts[dst], 1);
  }
}
__global__ __launch_bounds__(1024) void scan_kernel(const int* __restrict__ counts,
                                                    int* __restrict__ offs, int* __restrict__ cursor){
  __shared__ int sh[1024];
  const int t = threadIdx.x;
  int loc[16]; int s = 0;
#pragma unroll
  for (int i=0;i<16;i++){ loc[i] = counts[t*16+i]; s += loc[i]; }
  sh[t] = s; __syncthreads();
  for (int d=1; d<1024; d<<=1){
    int v = (t>=d) ? sh[t-d] : 0;
    __syncthreads(); sh[t] += v; __syncthreads();
  }
  int run = (t==0) ? 0 : sh[t-1];
#pragma unroll
  for (int i=0;i<16;i++){ offs[t*16+i] = run; cursor[t*16+i] = run; run += loc[i]; }
  if (t==1023) offs[NODES] = run;
}
__global__ void fill_kernel(const int* __restrict__ ei, int* __restrict__ cursor,
                            unsigned short* __restrict__ csr, int E){
  int i = blockIdx.x*blockDim.x + threadIdx.x;
  if (i < 2*E){
    int src = ei[i];
    int dst = (i < E) ? ei[E+i] : ei[i-E];
    int pos = atomicAdd(&cursor[dst], 1);
    csr[pos] = (unsigned short)src;
  }
}

// ---------------- prep: split x + transpose/split all weights to bf16 pairs ----------------
struct PrepArgs {
  const float *x,*W1,*W2,*wv,*wo,*f1,*f2;
  bf16 *xh,*xl,*w1h,*w1l,*w2h,*w2l,*wvh,*wvl,*woh,*wol,*f1h,*f1l,*f2h,*f2l;
};
__global__ void prep_kernel(PrepArgs P){
  int i = blockIdx.x*blockDim.x + threadIdx.x;
  if (i < 2097152){ split_store(P.xh, P.xl, i, P.x[i]); return; }
  i -= 2097152;
  if (i < 65536){ split_store(P.w1h, P.w1l, i, P.W1[(i&127)*512 + (i>>7)]); return; }   // K=128,N=512
  i -= 65536;
  if (i < 262144){ split_store(P.w2h, P.w2l, i, P.W2[(i&511)*512 + (i>>9)]); return; }  // 512,512
  i -= 262144;
  if (i < 16384){ split_store(P.wvh, P.wvl, i, P.wv[(i&127)*128 + (i>>7)]); return; }   // 128,128
  i -= 16384;
  if (i < 16384){ split_store(P.woh, P.wol, i, P.wo[(i&127)*128 + (i>>7)]); return; }
  i -= 16384;
  if (i < 65536){ split_store(P.f1h, P.f1l, i, P.f1[(i&127)*512 + (i>>7)]); return; }   // 128,512
  i -= 65536;
  if (i < 65536){ split_store(P.f2h, P.f2l, i, P.f2[(i&511)*128 + (i>>9)]); return; }   // 512,128
}

// ---------------- MFMA GEMM: C[MxN] = (Ah+Al) @ (Bh+Bl) with B stored transposed ----------------
static __device__ __forceinline__ short8v ld8(const bf16* p){
  return *(const short8v*)(const void*)(p);
}
template<int K, int SA, int SB, int ACT, int OMODE, int WPB>
__global__ __launch_bounds__(256) void mgemm(
    const bf16* __restrict__ Ah, const bf16* __restrict__ Al,
    const bf16* __restrict__ Bh, const bf16* __restrict__ Bl,
    const float* __restrict__ bias,
    float* __restrict__ Cf, bf16* __restrict__ Ch, bf16* __restrict__ Cl, int N){
  const int l = threadIdx.x & 63, w = threadIdx.x >> 6;
  const int lg = l >> 4, lr = l & 15;
  const int r0 = (blockIdx.y*WPB + w)*64;
  const int c0 = blockIdx.x*64;
  f32x4 acc[4][4] = {};
  int abase[4], bbase[4];
#pragma unroll
  for (int f=0; f<4; f++){
    abase[f] = (r0 + f*16 + lr)*K + lg*8;
    bbase[f] = (c0 + f*16 + lr)*K + lg*8;
  }
#pragma unroll
  for (int k0 = 0; k0 < K; k0 += 32){
    short8v ah[4], alo[4], bh[4], blo[4];
#pragma unroll
    for (int f=0; f<4; f++){
      ah[f] = ld8(Ah + abase[f] + k0);
      if (SA) alo[f] = ld8(Al + abase[f] + k0);
      bh[f] = ld8(Bh + bbase[f] + k0);
      if (SB) blo[f] = ld8(Bl + bbase[f] + k0);
    }
#pragma unroll
    for (int fm=0; fm<4; fm++)
#pragma unroll
      for (int fn=0; fn<4; fn++){
        acc[fm][fn] = __builtin_amdgcn_mfma_f32_16x16x32_bf16(ah[fm], bh[fn], acc[fm][fn], 0,0,0);
        if (SB) acc[fm][fn] = __builtin_amdgcn_mfma_f32_16x16x32_bf16(ah[fm], blo[fn], acc[fm][fn], 0,0,0);
        if (SA) acc[fm][fn] = __builtin_amdgcn_mfma_f32_16x16x32_bf16(alo[fm], bh[fn], acc[fm][fn], 0,0,0);
      }
  }
#pragma unroll
  for (int fm=0; fm<4; fm++){
#pragma unroll
    for (int fn=0; fn<4; fn++){
      const int col = c0 + fn*16 + lr;
      const float bv = bias ? bias[col] : 0.f;
#pragma unroll
      for (int r=0; r<4; r++){
        const int row = r0 + fm*16 + lg*4 + r;
        float v = acc[fm][fn][r] + bv;
        if (ACT==1) v = fmaxf(v, 0.f);
        const size_t idx = (size_t)row*N + col;
        if (OMODE==0) Cf[idx] = v;
        else if (OMODE==1) Ch[idx] = __float2bfloat16(v);
        else split_store(Ch, Cl, idx, v);
      }
    }
  }
}

// ---------------- attention coefficients ----------------
__global__ __launch_bounds__(256) void alsald_kernel(const bf16* __restrict__ h,
    const float* __restrict__ a_s, const float* __restrict__ a_d,
    float* __restrict__ als, float* __restrict__ ald){
  int n = blockIdx.x;
  int w = threadIdx.x >> 6, lane = threadIdx.x & 63;
  int c = w*128 + lane*2;
  bf162 hv = *(const bf162*)&h[(size_t)n*FEAT + c];
  float hx = __bfloat162float(hv.x), hy = __bfloat162float(hv.y);
  float2 as2 = *(const float2*)&a_s[c];
  float2 ad2 = *(const float2*)&a_d[c];
  float s = hx*as2.x + hy*as2.y;
  float d = hx*ad2.x + hy*ad2.y;
#pragma unroll
  for (int o=32;o>0;o>>=1){ s += __shfl_xor(s,o); d += __shfl_xor(d,o); }
  if (lane == 0){ als[n*4+w] = s; ald[n*4+w] = d; }
}

// ---------------- fused GAT aggregation: softmax (phase 1) + weighted gather (phase 2) ----------------
// one wave per node; no LDS, no extra kernel. CONCAT=false fuses head-mean + b2 + pe + q-split.
template<bool CONCAT>
__global__ __launch_bounds__(256) void gat_fused_kernel(const bf16* __restrict__ hfeat,
    const float* __restrict__ als, const float* __restrict__ ald,
    const int* __restrict__ offs, const unsigned short* __restrict__ csr,
    const float* __restrict__ bias, void* __restrict__ outv,
    bf16* __restrict__ qh, bf16* __restrict__ ql){
  const int w = threadIdx.x >> 6, l = threadIdx.x & 63, g = l >> 4;
  const int nb = blockIdx.x;
  const int n = (nb & 7)*2048 + (nb >> 3)*4 + w;   // cluster-contiguous, XCD-aligned
  const float4 ad4 = *(const float4*)&ald[(size_t)n*4];
  const int beg = offs[n];
  const int cnt = offs[n+1] - beg + 1;             // + implicit self-loop
  // ---- phase 1: lane-parallel online softmax (m, den) over edges ----
  float m0=-1e30f,m1=-1e30f,m2=-1e30f,m3=-1e30f;
  float d0=0.f,d1=0.f,d2=0.f,d3=0.f;
  for (int i = l; i < cnt; i += 64){
    const int src = (i < cnt-1) ? (int)csr[beg+i] : n;
    const float4 as4 = *(const float4*)&als[(size_t)src*4];
    float e0 = as4.x + ad4.x; e0 = e0>0.f?e0:0.2f*e0;
    float e1 = as4.y + ad4.y; e1 = e1>0.f?e1:0.2f*e1;
    float e2 = as4.z + ad4.z; e2 = e2>0.f?e2:0.2f*e2;
    float e3 = as4.w + ad4.w; e3 = e3>0.f?e3:0.2f*e3;
    float n0=fmaxf(m0,e0); d0=d0*__expf(m0-n0)+__expf(e0-n0); m0=n0;
    float n1=fmaxf(m1,e1); d1=d1*__expf(m1-n1)+__expf(e1-n1); m1=n1;
    float n2=fmaxf(m2,e2); d2=d2*__expf(m2-n2)+__expf(e2-n2); m2=n2;
    float n3=fmaxf(m3,e3); d3=d3*__expf(m3-n3)+__expf(e3-n3); m3=n3;
  }
#pragma unroll
  for (int o=32;o>0;o>>=1){
    float mo, dd, nm;
    mo=__shfl_xor(m0,o); dd=__shfl_xor(d0,o); nm=fmaxf(m0,mo);
    d0=d0*__expf(m0-nm)+dd*__expf(mo-nm); m0=nm;
    mo=__shfl_xor(m1,o); dd=__shfl_xor(d1,o); nm=fmaxf(m1,mo);
    d1=d1*__expf(m1-nm)+dd*__expf(mo-nm); m1=nm;
    mo=__shfl_xor(m2,o); dd=__shfl_xor(d2,o); nm=fmaxf(m2,mo);
    d2=d2*__expf(m2-nm)+dd*__expf(mo-nm); m2=nm;
    mo=__shfl_xor(m3,o); dd=__shfl_xor(d3,o); nm=fmaxf(m3,mo);
    d3=d3*__expf(m3-nm)+dd*__expf(mo-nm); m3=nm;
  }
  const float C0 = __expf(-m0)/(d0+1e-16f);
  const float C1 = __expf(-m1)/(d1+1e-16f);
  const float C2 = __expf(-m2)/(d2+1e-16f);
  const float C3 = __expf(-m3)/(d3+1e-16f);
  const float Cg  = g==0?C0 : g==1?C1 : g==2?C2 : C3;
  const float adg = g==0?ad4.x : g==1?ad4.y : g==2?ad4.z : ad4.w;
  // ---- phase 2: serial edge loop, alpha = exp(e)*Cg, all 64 lanes on features ----
  float acc[8] = {0,0,0,0,0,0,0,0};
  const int nE = cnt - 1;
#pragma unroll 4
  for (int i = 0; i < nE; ++i){
    const int src = (int)csr[beg+i];
    float e = als[(size_t)src*4 + g] + adg;
    e = e > 0.f ? e : 0.2f*e;
    const float a = __expf(e) * Cg;
    const short8v hv = *(const short8v*)(const void*)&hfeat[(size_t)src*FEAT + l*8];
#pragma unroll
    for (int j=0;j<8;j++) acc[j] += a * b2f(hv[j]);
  }
  { // self loop (last, preserving summation order)
    float e = als[(size_t)n*4 + g] + adg;
    e = e > 0.f ? e : 0.2f*e;
    const float a = __expf(e) * Cg;
    const short8v hv = *(const short8v*)(const void*)&hfeat[(size_t)n*FEAT + l*8];
#pragma unroll
    for (int j=0;j<8;j++) acc[j] += a * b2f(hv[j]);
  }
  if (CONCAT){
    short8v ov;
#pragma unroll
    for (int j=0;j<8;j++){
      float v = acc[j] + bias[l*8+j];
      v = v > 0.f ? v : expm1f(v);               // fused ELU
      bf16 bv = __float2bfloat16(v);
      ov[j] = (short)*(unsigned short*)&bv;
    }
    *(short8v*)((char*)outv + ((size_t)n*FEAT + l*8)*2) = ov;
  } else {
#pragma unroll
    for (int j=0;j<8;j++){
      acc[j] += __shfl_xor(acc[j], 16);
      acc[j] += __shfl_xor(acc[j], 32);
    }
    if (l < 16){
      float* op = (float*)outv + (size_t)n*128 + l*8;
#pragma unroll
      for (int j=0;j<8;j++){
        const int col = l*8 + j;
        float v = 0.25f*acc[j] + bias[col];
        // fused pe[L-1] add + q bf16-split
        float ex = __expf((float)(col & ~1) * (-9.210340371976184f/128.f));
        float pe = (col & 1) ? cosf(4.f*ex) : sinf(4.f*ex);
        float q = v + pe;
        op[j] = q;
        split_store(qh, ql, (size_t)n*128 + col, q);
      }
    }
  }
}

// ---------------- LayerNorm(a+b), optional bf16 split output ----------------
template<int SPLIT>
__global__ __launch_bounds__(256) void ln_kernel(const float* __restrict__ a, const float* __restrict__ b,
    const float* __restrict__ g, const float* __restrict__ bb, float* __restrict__ out,
    bf16* __restrict__ oh, bf16* __restrict__ ol){
  int row = blockIdx.x*4 + (threadIdx.x >> 6);
  int lane = threadIdx.x & 63;
  int c = lane*2;
  float2 va = *(const float2*)&a[(size_t)row*128 + c];
  float2 vb = *(const float2*)&b[(size_t)row*128 + c];
  float x0 = va.x+vb.x, x1 = va.y+vb.y;
  float s = x0+x1, q = x0*x0 + x1*x1;
#pragma unroll
  for (int o=32;o>0;o>>=1){ s += __shfl_xor(s,o); q += __shfl_xor(q,o); }
  float mu = s*(1.f/128.f);
  float var = q*(1.f/128.f) - mu*mu;
  float r = 1.f/sqrtf(var + 1e-5f);
  float y0 = (x0-mu)*r*g[c]   + bb[c];
  float y1 = (x1-mu)*r*g[c+1] + bb[c+1];
  size_t idx = (size_t)row*128 + c;
  out[idx] = y0; out[idx+1] = y1;
  if (SPLIT){ split_store(oh, ol, idx, y0); split_store(oh, ol, idx+1, y1); }
}

// ---------------- fused LayerNorm2 + classifier head ----------------
__global__ __launch_bounds__(256) void ln_final_kernel(const float* __restrict__ a, const float* __restrict__ b,
    const float* __restrict__ g, const float* __restrict__ bb,
    const float* __restrict__ wc, const float* __restrict__ bc,
    float* __restrict__ out){
  int row = blockIdx.x*4 + (threadIdx.x >> 6);
  int lane = threadIdx.x & 63;
  int c = lane*2;
  float2 va = *(const float2*)&a[(size_t)row*128 + c];
  float2 vb = *(const float2*)&b[(size_t)row*128 + c];
  float x0 = va.x+vb.x, x1 = va.y+vb.y;
  float s = x0+x1, q = x0*x0 + x1*x1;
#pragma unroll
  for (int o=32;o>0;o>>=1){ s += __shfl_xor(s,o); q += __shfl_xor(q,o); }
  float mu = s*(1.f/128.f);
  float var = q*(1.f/128.f) - mu*mu;
  float r = 1.f/sqrtf(var + 1e-5f);
  float y0 = (x0-mu)*r*g[c]   + bb[c];
  float y1 = (x1-mu)*r*g[c+1] + bb[c+1];
  float s0 = y0*wc[c*2]   + y1*wc[(c+1)*2];
  float s1 = y0*wc[c*2+1] + y1*wc[(c+1)*2+1];
#pragma unroll
  for (int o=32;o>0;o>>=1){ s0 += __shfl_xor(s0,o); s1 += __shfl_xor(s1,o); }
  if (lane == 0){
    out[row*2]   = s0 + bc[0];
    out[row*2+1] = s1 + bc[1];
  }
}

extern "C" void kernel_launch(void* const* d_in, const int* in_sizes, int n_in,
                              void* d_out, int out_size, void* d_ws, size_t ws_size,
                              hipStream_t stream){
  const float* x      = (const float*)d_in[0];
  const int*   ei     = (const int*)d_in[1];
  const float* W1     = (const float*)d_in[3];
  const float* a_src1 = (const float*)d_in[4];
  const float* a_dst1 = (const float*)d_in[5];
  const float* b1     = (const float*)d_in[6];
  const float* W2     = (const float*)d_in[7];
  const float* a_src2 = (const float*)d_in[8];
  const float* a_dst2 = (const float*)d_in[9];
  const float* b2     = (const float*)d_in[10];
  const float* wv     = (const float*)d_in[15];
  const float* bv     = (const float*)d_in[16];
  const float* wo     = (const float*)d_in[17];
  const float* bo     = (const float*)d_in[18];
  const float* ln_g   = (const float*)d_in[19];
  const float* ln_b   = (const float*)d_in[20];
  const float* f1     = (const float*)d_in[21];
  const float* fb1    = (const float*)d_in[22];
  const float* f2     = (const float*)d_in[23];
  const float* fb2    = (const float*)d_in[24];
  const float* wc     = (const float*)d_in[25];
  const float* bc     = (const float*)d_in[26];
  float* outp = (float*)d_out;

  const int E = in_sizes[1] / 2;
  const int n = NODES;
  const int tE = 2*E;
  const size_t MB = 1024*1024;

  const size_t NEED = 36*MB;
  if (ws_size < NEED){
    sentinel_kernel<<<(out_size+255)/256, 256, 0, stream>>>(outp, out_size,
        1000.0f + (float)(ws_size / MB));
    return;
  }

  // ---- arena [0,36) MB; liveness audited phase-by-phase ----
  char* base = (char*)d_ws;
  int* counts = (int*)(base + 0);            // [0,64K)  (pre-gemm1 only)
  int* cursor = (int*)(base + 65536);        // [64K,128K)
  bf16*  h1    = (bf16*)(base + 0);          // [0,16): gemm1 out
  bf16*  xh    = (bf16*)(base + 16*MB);      // [16,20)
  bf16*  xl    = (bf16*)(base + 20*MB);      // [20,24)
  bf16*  h     = (bf16*)(base + 16*MB);      // [16,32): agg1 out (xh/xl dead)
  bf16*  h2f   = (bf16*)(base + 0);          // [0,16): gemm2 out (h1 dead)
  float* h2q   = (float*)(base + 16*MB);     // [16,24): agg2 out = q (h dead)
  bf16*  qh    = (bf16*)(base + 24*MB);      // [24,28)
  bf16*  ql    = (bf16*)(base + 28*MB);      // [28,32)
  bf16*  vh    = (bf16*)(base + 0);          // [0,4)   (h2f dead)
  bf16*  vl    = (bf16*)(base + 4*MB);       // [4,8)
  float* aobuf = (float*)(base + 8*MB);      // [8,16)
  float* y1    = (float*)(base + 24*MB);     // [24,32) (qh/ql dead)
  bf16*  y1h   = (bf16*)(base + 0);          // [0,4)   (vh/vl dead)
  bf16*  y1l   = (bf16*)(base + 4*MB);       // [4,8)
  bf16*  hidden= (bf16*)(base + 8*MB);       // [8,24) 16MB (aobuf,h2q dead)
  float* ffn2f = (float*)(base + 0);         // [0,8)   (y1h/l dead after ffn1)
  // S region [32,36)
  char* u = base + 32*MB;
  bf16* w1h = (bf16*)u; u += 131072;  bf16* w1l = (bf16*)u; u += 131072;
  bf16* w2h = (bf16*)u; u += 524288;  bf16* w2l = (bf16*)u; u += 524288;
  bf16* wvh = (bf16*)u; u += 32768;   bf16* wvl = (bf16*)u; u += 32768;
  bf16* woh = (bf16*)u; u += 32768;   bf16* wol = (bf16*)u; u += 32768;
  bf16* f1h = (bf16*)u; u += 131072;  bf16* f1l = (bf16*)u; u += 131072;
  bf16* f2h = (bf16*)u; u += 131072;  bf16* f2l = (bf16*)u; u += 131072;
  float* als  = (float*)u; u += (size_t)n*4*4;
  float* ald  = (float*)u; u += (size_t)n*4*4;
  int* offs   = (int*)u;   u += (size_t)(n+1)*4 + 252;
  unsigned short* csr = (unsigned short*)u; u += (size_t)tE*2;

  // ---- prep + CSR ----
  PrepArgs P = { x,W1,W2,wv,wo,f1,f2, xh,xl,w1h,w1l,w2h,w2l,wvh,wvl,woh,wol,f1h,f1l,f2h,f2l };
  prep_kernel<<<(2588672+255)/256, 256, 0, stream>>>(P);
  zero_kernel<<<(n+255)/256, 256, 0, stream>>>(counts, n);
  count_kernel<<<(tE+255)/256, 256, 0, stream>>>(ei, counts, E);
  scan_kernel<<<1, 1024, 0, stream>>>(counts, offs, cursor);
  fill_kernel<<<(tE+255)/256, 256, 0, stream>>>(ei, cursor, csr, E);

  // ---- GAT layer 1 ----
  mgemm<128,1,1,0,1,4><<<dim3(8,64), 256, 0, stream>>>(xh, xl, w1h, w1l, nullptr, nullptr, h1, nullptr, 512);
  alsald_kernel<<<n, 256, 0, stream>>>(h1, a_src1, a_dst1, als, ald);
  gat_fused_kernel<true><<<n/4, 256, 0, stream>>>(h1, als, ald, offs, csr, b1, h, nullptr, nullptr);

  // ---- GAT layer 2 ----
  mgemm<512,0,1,0,1,4><<<dim3(8,64), 256, 0, stream>>>(h, nullptr, w2h, w2l, nullptr, nullptr, h2f, nullptr, 512);
  alsald_kernel<<<n, 256, 0, stream>>>(h2f, a_src2, a_dst2, als, ald);
  gat_fused_kernel<false><<<n/4, 256, 0, stream>>>(h2f, als, ald, offs, csr, b2, h2q, qh, ql);

  // ---- temporal attention (collapsed to V at l=L-1) + head ----
  mgemm<128,1,1,0,2,1><<<dim3(2,256), 64, 0, stream>>>(qh, ql, wvh, wvl, bv, nullptr, vh, vl, 128);
  mgemm<128,1,1,0,0,1><<<dim3(2,256), 64, 0, stream>>>(vh, vl, woh, wol, bo, aobuf, nullptr, nullptr, 128);
  ln_kernel<1><<<n/4, 256, 0, stream>>>(h2q, aobuf, ln_g, ln_b, y1, y1h, y1l);
  mgemm<128,1,1,1,1,4><<<dim3(8,64), 256, 0, stream>>>(y1h, y1l, f1h, f1l, fb1, nullptr, hidden, nullptr, 512);
  mgemm<512,0,1,0,0,1><<<dim3(2,256), 64, 0, stream>>>(hidden, nullptr, f2h, f2l, fb2, ffn2f, nullptr, nullptr, 128);
  ln_final_kernel<<<n/4, 256, 0, stream>>>(y1, ffn2f, ln_g, ln_b, wc, bc, outp);
}

// Round 11
// 341.828 us; speedup vs baseline: 2.1192x; 1.0441x over previous
//
#include <hip/hip_runtime.h>
#include <hip/hip_bf16.h>

#define NODES 16384
#define FEAT 512
typedef __hip_bfloat16 bf16;
typedef __hip_bfloat162 bf162;
typedef short short8v __attribute__((ext_vector_type(8)));
typedef float f32x4 __attribute__((ext_vector_type(4)));

static __device__ __forceinline__ float b2f(short s){
  return __uint_as_float(((unsigned)(unsigned short)s) << 16);
}
static __device__ __forceinline__ void split_store(bf16* h, bf16* l, size_t i, float v){
  bf16 hi = __float2bfloat16(v);
  h[i] = hi; l[i] = __float2bfloat16(v - __bfloat162float(hi));
}

// ---------------- diagnostic sentinel ----------------
__global__ void sentinel_kernel(float* __restrict__ out, int n, float v){
  int i = blockIdx.x*blockDim.x + threadIdx.x;
  if (i < n) out[i] = v;
}

// ---------------- CSR build ----------------
__global__ void zero_kernel(int* __restrict__ p, int n){
  int i = blockIdx.x*blockDim.x + threadIdx.x;
  if (i < n) p[i] = 0;
}
__global__ void count_kernel(const int* __restrict__ ei, int* __restrict__ counts, int E){
  int i = blockIdx.x*blockDim.x + threadIdx.x;
  if (i < 2*E){
    int dst = (i < E) ? ei[E+i] : ei[i-E];
    atomicAdd(&counts[dst], 1);
  }
}
__global__ __launch_bounds__(1024) void scan_kernel(const int* __restrict__ counts,
                                                    int* __restrict__ offs, int* __restrict__ cursor){
  __shared__ int sh[1024];
  const int t = threadIdx.x;
  int loc[16]; int s = 0;
#pragma unroll
  for (int i=0;i<16;i++){ loc[i] = counts[t*16+i]; s += loc[i]; }
  sh[t] = s; __syncthreads();
  for (int d=1; d<1024; d<<=1){
    int v = (t>=d) ? sh[t-d] : 0;
    __syncthreads(); sh[t] += v; __syncthreads();
  }
  int run = (t==0) ? 0 : sh[t-1];
#pragma unroll
  for (int i=0;i<16;i++){ offs[t*16+i] = run; cursor[t*16+i] = run; run += loc[i]; }
  if (t==1023) offs[NODES] = run;
}
__global__ void fill_kernel(const int* __restrict__ ei, int* __restrict__ cursor,
                            unsigned short* __restrict__ csr, int E){
  int i = blockIdx.x*blockDim.x + threadIdx.x;
  if (i < 2*E){
    int src = ei[i];
    int dst = (i < E) ? ei[E+i] : ei[i-E];
    int pos = atomicAdd(&cursor[dst], 1);
    csr[pos] = (unsigned short)src;
  }
}

// ---------------- prep: split x + transpose/split all weights to bf16 pairs ----------------
struct PrepArgs {
  const float *x,*W1,*W2,*wv,*wo,*f1,*f2;
  bf16 *xh,*xl,*w1h,*w1l,*w2h,*w2l,*wvh,*wvl,*woh,*wol,*f1h,*f1l,*f2h,*f2l;
};
__global__ void prep_kernel(PrepArgs P){
  int i = blockIdx.x*blockDim.x + threadIdx.x;
  if (i < 2097152){ split_store(P.xh, P.xl, i, P.x[i]); return; }
  i -= 2097152;
  if (i < 65536){ split_store(P.w1h, P.w1l, i, P.W1[(i&127)*512 + (i>>7)]); return; }   // K=128,N=512
  i -= 65536;
  if (i < 262144){ split_store(P.w2h, P.w2l, i, P.W2[(i&511)*512 + (i>>9)]); return; }  // 512,512
  i -= 262144;
  if (i < 16384){ split_store(P.wvh, P.wvl, i, P.wv[(i&127)*128 + (i>>7)]); return; }   // 128,128
  i -= 16384;
  if (i < 16384){ split_store(P.woh, P.wol, i, P.wo[(i&127)*128 + (i>>7)]); return; }
  i -= 16384;
  if (i < 65536){ split_store(P.f1h, P.f1l, i, P.f1[(i&127)*512 + (i>>7)]); return; }   // 128,512
  i -= 65536;
  if (i < 65536){ split_store(P.f2h, P.f2l, i, P.f2[(i&511)*128 + (i>>9)]); return; }   // 512,128
}

// ---------------- MFMA GEMM: C[MxN] = (Ah+Al) @ (Bh+Bl) with B stored transposed ----------------
static __device__ __forceinline__ short8v ld8(const bf16* p){
  return *(const short8v*)(const void*)(p);
}
template<int K, int SA, int SB, int ACT, int OMODE, int WPB>
__global__ __launch_bounds__(256) void mgemm(
    const bf16* __restrict__ Ah, const bf16* __restrict__ Al,
    const bf16* __restrict__ Bh, const bf16* __restrict__ Bl,
    const float* __restrict__ bias,
    float* __restrict__ Cf, bf16* __restrict__ Ch, bf16* __restrict__ Cl, int N){
  const int l = threadIdx.x & 63, w = threadIdx.x >> 6;
  const int lg = l >> 4, lr = l & 15;
  const int r0 = (blockIdx.y*WPB + w)*64;
  const int c0 = blockIdx.x*64;
  f32x4 acc[4][4] = {};
  int abase[4], bbase[4];
#pragma unroll
  for (int f=0; f<4; f++){
    abase[f] = (r0 + f*16 + lr)*K + lg*8;
    bbase[f] = (c0 + f*16 + lr)*K + lg*8;
  }
#pragma unroll
  for (int k0 = 0; k0 < K; k0 += 32){
    short8v ah[4], alo[4], bh[4], blo[4];
#pragma unroll
    for (int f=0; f<4; f++){
      ah[f] = ld8(Ah + abase[f] + k0);
      if (SA) alo[f] = ld8(Al + abase[f] + k0);
      bh[f] = ld8(Bh + bbase[f] + k0);
      if (SB) blo[f] = ld8(Bl + bbase[f] + k0);
    }
#pragma unroll
    for (int fm=0; fm<4; fm++)
#pragma unroll
      for (int fn=0; fn<4; fn++){
        acc[fm][fn] = __builtin_amdgcn_mfma_f32_16x16x32_bf16(ah[fm], bh[fn], acc[fm][fn], 0,0,0);
        if (SB) acc[fm][fn] = __builtin_amdgcn_mfma_f32_16x16x32_bf16(ah[fm], blo[fn], acc[fm][fn], 0,0,0);
        if (SA) acc[fm][fn] = __builtin_amdgcn_mfma_f32_16x16x32_bf16(alo[fm], bh[fn], acc[fm][fn], 0,0,0);
      }
  }
#pragma unroll
  for (int fm=0; fm<4; fm++){
#pragma unroll
    for (int fn=0; fn<4; fn++){
      const int col = c0 + fn*16 + lr;
      const float bv = bias ? bias[col] : 0.f;
#pragma unroll
      for (int r=0; r<4; r++){
        const int row = r0 + fm*16 + lg*4 + r;
        float v = acc[fm][fn][r] + bv;
        if (ACT==1) v = fmaxf(v, 0.f);
        const size_t idx = (size_t)row*N + col;
        if (OMODE==0) Cf[idx] = v;
        else if (OMODE==1) Ch[idx] = __float2bfloat16(v);
        else split_store(Ch, Cl, idx, v);
      }
    }
  }
}

// ---------------- attention coefficients ----------------
__global__ __launch_bounds__(256) void alsald_kernel(const bf16* __restrict__ h,
    const float* __restrict__ a_s, const float* __restrict__ a_d,
    float* __restrict__ als, float* __restrict__ ald){
  int n = blockIdx.x;
  int w = threadIdx.x >> 6, lane = threadIdx.x & 63;
  int c = w*128 + lane*2;
  bf162 hv = *(const bf162*)&h[(size_t)n*FEAT + c];
  float hx = __bfloat162float(hv.x), hy = __bfloat162float(hv.y);
  float2 as2 = *(const float2*)&a_s[c];
  float2 ad2 = *(const float2*)&a_d[c];
  float s = hx*as2.x + hy*as2.y;
  float d = hx*ad2.x + hy*ad2.y;
#pragma unroll
  for (int o=32;o>0;o>>=1){ s += __shfl_xor(s,o); d += __shfl_xor(d,o); }
  if (lane == 0){ als[n*4+w] = s; ald[n*4+w] = d; }
}

// ---------------- fused GAT aggregation: register-cached alpha + shuffle broadcast ----------------
// one wave per node. Lane l = (head l>>4, edge-slot l&15); alpha for edges (l&15)+16p held in
// registers (6 pages = 96 edges; inline fallback beyond). Phase 2 broadcasts (alpha,src) via shfl.
template<bool CONCAT>
__global__ __launch_bounds__(256) void gat_fused_kernel(const bf16* __restrict__ hfeat,
    const float* __restrict__ als, const float* __restrict__ ald,
    const int* __restrict__ offs, const unsigned short* __restrict__ csr,
    const float* __restrict__ bias, void* __restrict__ outv,
    bf16* __restrict__ qh, bf16* __restrict__ ql){
  const int w = threadIdx.x >> 6, l = threadIdx.x & 63, g = l >> 4, s16 = l & 15;
  const int nb = blockIdx.x;
  const int n = (nb & 7)*2048 + (nb >> 3)*4 + w;   // cluster-contiguous, XCD-aligned
  const float adg = ald[(size_t)n*4 + g];
  const int beg = offs[n];
  const int cnt = offs[n+1] - beg + 1;             // + implicit self-loop (edge cnt-1)
  // ---- phase 1: per-head-lane e for edges s16+16p ----
  float ev[6]; int sv[6];
#pragma unroll
  for (int p=0;p<6;p++){
    const int i = s16 + p*16;
    int src = n;
    float e = -1e30f;
    if (i < cnt){
      if (i < cnt-1) src = (int)csr[beg+i];
      float t = als[(size_t)src*4+g] + adg;
      e = fmaxf(t, 0.2f*t);                        // leaky_relu 0.2
    }
    ev[p] = e; sv[p] = src;
  }
  float m = -1e30f;
#pragma unroll
  for (int p=0;p<6;p++) m = fmaxf(m, ev[p]);
  float den = 0.f;
#pragma unroll
  for (int p=0;p<6;p++) den += (ev[p] > -1e29f) ? __expf(ev[p]-m) : 0.f;
  // butterfly merge (m,den) within the 16-lane head group
#pragma unroll
  for (int mask=1; mask<16; mask<<=1){
    float mo = __shfl_xor(m, mask);
    float dd = __shfl_xor(den, mask);
    float nm = fmaxf(m, mo);
    den = den*__expf(m-nm) + dd*__expf(mo-nm);
    m = nm;
  }
  const float C = __expf(-m)/(den + 1e-16f);
#pragma unroll
  for (int p=0;p<6;p++) ev[p] = (ev[p] > -1e29f) ? __expf(ev[p])*C : 0.f;  // ev := alpha
  // ---- phase 2: weighted gather; (alpha,src) broadcast via shfl ----
  float acc[8] = {0,0,0,0,0,0,0,0};
  const int fb = l*8;
#pragma unroll
  for (int p=0;p<6;p++){
    const int pbase = p*16;
    if (pbase < cnt){
      const int lim = (cnt - pbase < 16) ? (cnt - pbase) : 16;
      for (int j=0;j<lim;++j){
        const int sel = (l & 48) | j;
        const float a = __shfl(ev[p], sel);
        const int src = __shfl(sv[p], sel);
        const short8v hv = *(const short8v*)(const void*)&hfeat[(size_t)src*FEAT + fb];
#pragma unroll
        for (int k=0;k<8;k++) acc[k] += a * b2f(hv[k]);
      }
    }
  }
  // fallback for cnt > 96 (probabilistically absent; correctness guard)
  for (int i = 96; i < cnt; ++i){
    const int src = (i < cnt-1) ? (int)csr[beg+i] : n;
    float t = als[(size_t)src*4+g] + adg;
    t = fmaxf(t, 0.2f*t);
    const float a = __expf(t)*C;
    const short8v hv = *(const short8v*)(const void*)&hfeat[(size_t)src*FEAT + fb];
#pragma unroll
    for (int k=0;k<8;k++) acc[k] += a * b2f(hv[k]);
  }
  if (CONCAT){
    short8v ov;
#pragma unroll
    for (int j=0;j<8;j++){
      float v = acc[j] + bias[fb+j];
      v = v > 0.f ? v : expm1f(v);               // fused ELU
      bf16 bv = __float2bfloat16(v);
      ov[j] = (short)*(unsigned short*)&bv;
    }
    *(short8v*)((char*)outv + ((size_t)n*FEAT + fb)*2) = ov;
  } else {
#pragma unroll
    for (int j=0;j<8;j++){
      acc[j] += __shfl_xor(acc[j], 16);
      acc[j] += __shfl_xor(acc[j], 32);
    }
    if (l < 16){
      float* op = (float*)outv + (size_t)n*128 + l*8;
#pragma unroll
      for (int j=0;j<8;j++){
        const int col = l*8 + j;
        float v = 0.25f*acc[j] + bias[col];
        // fused pe[L-1] add + q bf16-split
        float ex = __expf((float)(col & ~1) * (-9.210340371976184f/128.f));
        float pe = (col & 1) ? cosf(4.f*ex) : sinf(4.f*ex);
        float q = v + pe;
        op[j] = q;
        split_store(qh, ql, (size_t)n*128 + col, q);
      }
    }
  }
}

// ---------------- LayerNorm(a+b), optional bf16 split output ----------------
template<int SPLIT>
__global__ __launch_bounds__(256) void ln_kernel(const float* __restrict__ a, const float* __restrict__ b,
    const float* __restrict__ g, const float* __restrict__ bb, float* __restrict__ out,
    bf16* __restrict__ oh, bf16* __restrict__ ol){
  int row = blockIdx.x*4 + (threadIdx.x >> 6);
  int lane = threadIdx.x & 63;
  int c = lane*2;
  float2 va = *(const float2*)&a[(size_t)row*128 + c];
  float2 vb = *(const float2*)&b[(size_t)row*128 + c];
  float x0 = va.x+vb.x, x1 = va.y+vb.y;
  float s = x0+x1, q = x0*x0 + x1*x1;
#pragma unroll
  for (int o=32;o>0;o>>=1){ s += __shfl_xor(s,o); q += __shfl_xor(q,o); }
  float mu = s*(1.f/128.f);
  float var = q*(1.f/128.f) - mu*mu;
  float r = 1.f/sqrtf(var + 1e-5f);
  float y0 = (x0-mu)*r*g[c]   + bb[c];
  float y1 = (x1-mu)*r*g[c+1] + bb[c+1];
  size_t idx = (size_t)row*128 + c;
  out[idx] = y0; out[idx+1] = y1;
  if (SPLIT){ split_store(oh, ol, idx, y0); split_store(oh, ol, idx+1, y1); }
}

// ---------------- fused LayerNorm2 + classifier head ----------------
__global__ __launch_bounds__(256) void ln_final_kernel(const float* __restrict__ a, const float* __restrict__ b,
    const float* __restrict__ g, const float* __restrict__ bb,
    const float* __restrict__ wc, const float* __restrict__ bc,
    float* __restrict__ out){
  int row = blockIdx.x*4 + (threadIdx.x >> 6);
  int lane = threadIdx.x & 63;
  int c = lane*2;
  float2 va = *(const float2*)&a[(size_t)row*128 + c];
  float2 vb = *(const float2*)&b[(size_t)row*128 + c];
  float x0 = va.x+vb.x, x1 = va.y+vb.y;
  float s = x0+x1, q = x0*x0 + x1*x1;
#pragma unroll
  for (int o=32;o>0;o>>=1){ s += __shfl_xor(s,o); q += __shfl_xor(q,o); }
  float mu = s*(1.f/128.f);
  float var = q*(1.f/128.f) - mu*mu;
  float r = 1.f/sqrtf(var + 1e-5f);
  float y0 = (x0-mu)*r*g[c]   + bb[c];
  float y1 = (x1-mu)*r*g[c+1] + bb[c+1];
  float s0 = y0*wc[c*2]   + y1*wc[(c+1)*2];
  float s1 = y0*wc[c*2+1] + y1*wc[(c+1)*2+1];
#pragma unroll
  for (int o=32;o>0;o>>=1){ s0 += __shfl_xor(s0,o); s1 += __shfl_xor(s1,o); }
  if (lane == 0){
    out[row*2]   = s0 + bc[0];
    out[row*2+1] = s1 + bc[1];
  }
}

extern "C" void kernel_launch(void* const* d_in, const int* in_sizes, int n_in,
                              void* d_out, int out_size, void* d_ws, size_t ws_size,
                              hipStream_t stream){
  const float* x      = (const float*)d_in[0];
  const int*   ei     = (const int*)d_in[1];
  const float* W1     = (const float*)d_in[3];
  const float* a_src1 = (const float*)d_in[4];
  const float* a_dst1 = (const float*)d_in[5];
  const float* b1     = (const float*)d_in[6];
  const float* W2     = (const float*)d_in[7];
  const float* a_src2 = (const float*)d_in[8];
  const float* a_dst2 = (const float*)d_in[9];
  const float* b2     = (const float*)d_in[10];
  const float* wv     = (const float*)d_in[15];
  const float* bv     = (const float*)d_in[16];
  const float* wo     = (const float*)d_in[17];
  const float* bo     = (const float*)d_in[18];
  const float* ln_g   = (const float*)d_in[19];
  const float* ln_b   = (const float*)d_in[20];
  const float* f1     = (const float*)d_in[21];
  const float* fb1    = (const float*)d_in[22];
  const float* f2     = (const float*)d_in[23];
  const float* fb2    = (const float*)d_in[24];
  const float* wc     = (const float*)d_in[25];
  const float* bc     = (const float*)d_in[26];
  float* outp = (float*)d_out;

  const int E = in_sizes[1] / 2;
  const int n = NODES;
  const int tE = 2*E;
  const size_t MB = 1024*1024;

  const size_t NEED = 36*MB;
  if (ws_size < NEED){
    sentinel_kernel<<<(out_size+255)/256, 256, 0, stream>>>(outp, out_size,
        1000.0f + (float)(ws_size / MB));
    return;
  }

  // ---- arena [0,36) MB; liveness audited phase-by-phase ----
  char* base = (char*)d_ws;
  int* counts = (int*)(base + 0);            // [0,64K)  (pre-gemm1 only)
  int* cursor = (int*)(base + 65536);        // [64K,128K)
  bf16*  h1    = (bf16*)(base + 0);          // [0,16): gemm1 out
  bf16*  xh    = (bf16*)(base + 16*MB);      // [16,20)
  bf16*  xl    = (bf16*)(base + 20*MB);      // [20,24)
  bf16*  h     = (bf16*)(base + 16*MB);      // [16,32): agg1 out (xh/xl dead)
  bf16*  h2f   = (bf16*)(base + 0);          // [0,16): gemm2 out (h1 dead)
  float* h2q   = (float*)(base + 16*MB);     // [16,24): agg2 out = q (h dead)
  bf16*  qh    = (bf16*)(base + 24*MB);      // [24,28)
  bf16*  ql    = (bf16*)(base + 28*MB);      // [28,32)
  bf16*  vh    = (bf16*)(base + 0);          // [0,4)   (h2f dead)
  bf16*  vl    = (bf16*)(base + 4*MB);       // [4,8)
  float* aobuf = (float*)(base + 8*MB);      // [8,16)
  float* y1    = (float*)(base + 24*MB);     // [24,32) (qh/ql dead)
  bf16*  y1h   = (bf16*)(base + 0);          // [0,4)   (vh/vl dead)
  bf16*  y1l   = (bf16*)(base + 4*MB);       // [4,8)
  bf16*  hidden= (bf16*)(base + 8*MB);       // [8,24) 16MB (aobuf,h2q dead)
  float* ffn2f = (float*)(base + 0);         // [0,8)   (y1h/l dead after ffn1)
  // S region [32,36)
  char* u = base + 32*MB;
  bf16* w1h = (bf16*)u; u += 131072;  bf16* w1l = (bf16*)u; u += 131072;
  bf16* w2h = (bf16*)u; u += 524288;  bf16* w2l = (bf16*)u; u += 524288;
  bf16* wvh = (bf16*)u; u += 32768;   bf16* wvl = (bf16*)u; u += 32768;
  bf16* woh = (bf16*)u; u += 32768;   bf16* wol = (bf16*)u; u += 32768;
  bf16* f1h = (bf16*)u; u += 131072;  bf16* f1l = (bf16*)u; u += 131072;
  bf16* f2h = (bf16*)u; u += 131072;  bf16* f2l = (bf16*)u; u += 131072;
  float* als  = (float*)u; u += (size_t)n*4*4;
  float* ald  = (float*)u; u += (size_t)n*4*4;
  int* offs   = (int*)u;   u += (size_t)(n+1)*4 + 252;
  unsigned short* csr = (unsigned short*)u; u += (size_t)tE*2;

  // ---- prep + CSR ----
  PrepArgs P = { x,W1,W2,wv,wo,f1,f2, xh,xl,w1h,w1l,w2h,w2l,wvh,wvl,woh,wol,f1h,f1l,f2h,f2l };
  prep_kernel<<<(2588672+255)/256, 256, 0, stream>>>(P);
  zero_kernel<<<(n+255)/256, 256, 0, stream>>>(counts, n);
  count_kernel<<<(tE+255)/256, 256, 0, stream>>>(ei, counts, E);
  scan_kernel<<<1, 1024, 0, stream>>>(counts, offs, cursor);
  fill_kernel<<<(tE+255)/256, 256, 0, stream>>>(ei, cursor, csr, E);

  // ---- GAT layer 1 ----
  mgemm<128,1,1,0,1,4><<<dim3(8,64), 256, 0, stream>>>(xh, xl, w1h, w1l, nullptr, nullptr, h1, nullptr, 512);
  alsald_kernel<<<n, 256, 0, stream>>>(h1, a_src1, a_dst1, als, ald);
  gat_fused_kernel<true><<<n/4, 256, 0, stream>>>(h1, als, ald, offs, csr, b1, h, nullptr, nullptr);

  // ---- GAT layer 2 ----
  mgemm<512,0,1,0,1,4><<<dim3(8,64), 256, 0, stream>>>(h, nullptr, w2h, w2l, nullptr, nullptr, h2f, nullptr, 512);
  alsald_kernel<<<n, 256, 0, stream>>>(h2f, a_src2, a_dst2, als, ald);
  gat_fused_kernel<false><<<n/4, 256, 0, stream>>>(h2f, als, ald, offs, csr, b2, h2q, qh, ql);

  // ---- temporal attention (collapsed to V at l=L-1) + head ----
  mgemm<128,1,1,0,2,1><<<dim3(2,256), 64, 0, stream>>>(qh, ql, wvh, wvl, bv, nullptr, vh, vl, 128);
  mgemm<128,1,1,0,0,1><<<dim3(2,256), 64, 0, stream>>>(vh, vl, woh, wol, bo, aobuf, nullptr, nullptr, 128);
  ln_kernel<1><<<n/4, 256, 0, stream>>>(h2q, aobuf, ln_g, ln_b, y1, y1h, y1l);
  mgemm<128,1,1,1,1,4><<<dim3(8,64), 256, 0, stream>>>(y1h, y1l, f1h, f1l, fb1, nullptr, hidden, nullptr, 512);
  mgemm<512,0,1,0,0,1><<<dim3(2,256), 64, 0, stream>>>(hidden, nullptr, f2h, f2l, fb2, ffn2f, nullptr, nullptr, 128);
  ln_final_kernel<<<n/4, 256, 0, stream>>>(y1, ffn2f, ln_g, ln_b, wc, bc, outp);
}